// Round 7
// baseline (1466.728 us; speedup 1.0000x reference)
//
#include <hip/hip_runtime.h>
#include <hip/hip_bf16.h>

#define N_NODES  100000
#define N_EDGES  300000
#define FEAT     256
#define N_GRAPHS 500
#define N_LAYERS 6
#define SCAN_B   1024
#define NP       100096ull   // padded node count for frag layout (782*128)

typedef __attribute__((ext_vector_type(8))) short v8s;   // 8 x bf16 bits (4 VGPRs)
typedef __attribute__((ext_vector_type(4))) float v4f;   // MFMA accumulator

__device__ __forceinline__ unsigned short f2bf(float f) {
    unsigned u = __float_as_uint(f);
    unsigned r = u + 0x7fffu + ((u >> 16) & 1u);   // RNE
    return (unsigned short)(r >> 16);
}
__device__ __forceinline__ float bf2f(unsigned short b) {
    return __uint_as_float(((unsigned)b) << 16);
}

// Fragment-native layout for a matrix with R rows:
//   elem(row, k) stored at ((k>>3)*R + row)*8 + (k&7)
// A wave's MFMA fragment load (16 consecutive rows x 16B) = 256B contiguous.

// ---- init: x (f32) -> xb (row-major bf16) + xf (frag bf16) ----
__global__ __launch_bounds__(256) void init_kernel(const float* __restrict__ x,
                                                   ushort* __restrict__ xb,
                                                   ushort* __restrict__ xf) {
    int i = blockIdx.x * 256 + threadIdx.x;           // per 4 elements
    if ((size_t)i * 4 >= (size_t)N_NODES * FEAT) return;
    float4 v = ((const float4*)x)[i];
    ushort4 b = make_ushort4(f2bf(v.x), f2bf(v.y), f2bf(v.z), f2bf(v.w));
    ((ushort4*)xb)[i] = b;
    int node = i >> 6;
    int k8   = (i & 63) >> 1;           // feat = (i&63)*4
    int e    = (i & 1) * 4;
    *(ushort4*)(xf + ((size_t)k8 * NP + node) * 8 + e) = b;
}

// ---- weights f32 -> bf16 frag layout [l][k8][256 rows][8] ----
__global__ __launch_bounds__(256) void wconv_kernel(const float* __restrict__ Wl,
                                                    const float* __restrict__ Wr,
                                                    ushort* __restrict__ wlb,
                                                    ushort* __restrict__ wrb) {
    int i = blockIdx.x * 256 + threadIdx.x;           // per 4 elements
    if ((size_t)i * 4 >= (size_t)N_LAYERS * FEAT * FEAT) return;
    float4 a = ((const float4*)Wl)[i];
    float4 b = ((const float4*)Wr)[i];
    int idx4 = i * 4;
    int l = idx4 >> 16;
    int r = (idx4 >> 8) & 255;          // W out-row = GEMM col
    int c = idx4 & 255;                 // W in-col  = GEMM k
    size_t dst = (size_t)l * 65536 + ((size_t)(c >> 3) * 256 + r) * 8 + (c & 7);
    *(ushort4*)(wlb + dst) = make_ushort4(f2bf(a.x), f2bf(a.y), f2bf(a.z), f2bf(a.w));
    *(ushort4*)(wrb + dst) = make_ushort4(f2bf(b.x), f2bf(b.y), f2bf(b.z), f2bf(b.w));
}

// ================= CSR construction (counting sort by dst) =================

__global__ __launch_bounds__(256) void hist_kernel(const int* __restrict__ dst,
                                                   unsigned* __restrict__ degu) {
    int e = blockIdx.x * 256 + threadIdx.x;
    if (e < N_EDGES) atomicAdd(&degu[dst[e]], 1u);
}

__global__ __launch_bounds__(SCAN_B) void scan_blocks(const unsigned* __restrict__ degu,
                                                      unsigned* __restrict__ excl,
                                                      unsigned* __restrict__ bsum) {
    __shared__ unsigned tmp[SCAN_B];
    int i = blockIdx.x * SCAN_B + threadIdx.x;
    unsigned v = (i < N_NODES) ? degu[i] : 0u;
    tmp[threadIdx.x] = v;
    __syncthreads();
    for (int off = 1; off < SCAN_B; off <<= 1) {
        unsigned add = (threadIdx.x >= off) ? tmp[threadIdx.x - off] : 0u;
        __syncthreads();
        tmp[threadIdx.x] += add;
        __syncthreads();
    }
    if (i < N_NODES) excl[i] = tmp[threadIdx.x] - v;
    if (threadIdx.x == SCAN_B - 1) bsum[blockIdx.x] = tmp[SCAN_B - 1];
}

__global__ void scan_tops(unsigned* __restrict__ bsum, int nb) {
    unsigned run = 0;
    for (int b = 0; b < nb; ++b) { unsigned t = bsum[b]; bsum[b] = run; run += t; }
}

__global__ __launch_bounds__(256) void finalize_rowptr(const unsigned* __restrict__ excl,
                                                       const unsigned* __restrict__ bsum,
                                                       unsigned* __restrict__ rowptr,
                                                       unsigned* __restrict__ cursor) {
    int i = blockIdx.x * 256 + threadIdx.x;
    if (i < N_NODES) {
        unsigned v = excl[i] + bsum[i / SCAN_B];
        rowptr[i] = v;
        cursor[i] = v;
    }
    if (i == N_NODES) rowptr[N_NODES] = N_EDGES;
}

__global__ __launch_bounds__(256) void scatter_kernel(const int* __restrict__ ei,
                                                      unsigned* __restrict__ cursor,
                                                      unsigned* __restrict__ col) {
    int e = blockIdx.x * 256 + threadIdx.x;
    if (e >= N_EDGES) return;
    int d = ei[N_EDGES + e];
    unsigned p = atomicAdd(&cursor[d], 1u);
    col[p] = (unsigned)ei[e];
}

// ---- per-graph [start,end) bounds from sorted batch: boundary detection ----
__global__ __launch_bounds__(256) void bounds_kernel(const int* __restrict__ batch,
                                                     unsigned* __restrict__ gs,
                                                     unsigned* __restrict__ ge) {
    int i = blockIdx.x * 256 + threadIdx.x;
    if (i >= N_NODES) return;
    int g = batch[i];
    int gp = (i == 0) ? -1 : batch[i - 1];
    if (g != gp) gs[g] = (unsigned)i;
    int gn = (i == N_NODES - 1) ? -1 : batch[i + 1];
    if (g != gn) ge[g] = (unsigned)(i + 1);
}

// ---- CSR mean-aggregate: one wave per node, writes FRAG layout meanb ----
__global__ __launch_bounds__(256) void agg_csr(const unsigned* __restrict__ rowptr,
                                               const unsigned* __restrict__ col,
                                               const ushort* __restrict__ xb,   // row-major
                                               ushort* __restrict__ meanf) {    // frag layout
    int node = blockIdx.x * 4 + (threadIdx.x >> 6);
    int lane = threadIdx.x & 63;
    if (node >= N_NODES) return;
    unsigned s = rowptr[node], e = rowptr[node + 1];
    float a0 = 0.f, a1 = 0.f, a2 = 0.f, a3 = 0.f;
    for (unsigned j = s; j < e; ++j) {
        unsigned src = col[j];
        ushort4 v = *(const ushort4*)(xb + (size_t)src * FEAT + lane * 4);
        a0 += bf2f(v.x); a1 += bf2f(v.y); a2 += bf2f(v.z); a3 += bf2f(v.w);
    }
    float r = 1.0f / fmaxf((float)(e - s), 1.0f);
    ushort4 o = make_ushort4(f2bf(a0 * r), f2bf(a1 * r), f2bf(a2 * r), f2bf(a3 * r));
    // feats lane*4..lane*4+3 -> k8 = lane>>1, e = (lane&1)*4
    *(ushort4*)(meanf + ((size_t)(lane >> 1) * NP + node) * 8 + (lane & 1) * 4) = o;
}

// ============================================================================
// No-LDS GEMM: xbn = bf16( relu([mean|x] @ [Wl|Wr]^T + bl) + x )
// All operands in frag-native layout -> coalesced global fragment loads.
// 256 thr = 4 waves (2x2 of 64x64), 128x128 tile, grid (782, 2).
// Fully unrolled K-loop (16 phases x 16 MFMA), depth-2 register prefetch,
// zero barriers. Occupancy: VGPR-limited, target 3 waves/SIMD.
// ============================================================================
__global__ __launch_bounds__(256, 3) void gemm_kernel(
        const ushort* __restrict__ Am,    // mean, frag [32][NP][8]
        const ushort* __restrict__ Ax,    // x,    frag [32][NP][8]
        const ushort* __restrict__ xrow,  // x, row-major (residual)
        const ushort* __restrict__ Bl,    // Wl slice, frag [32][256][8]
        const ushort* __restrict__ Br,    // Wr slice
        const float*  __restrict__ bias,  // bl slice [256]
        ushort* __restrict__ xbn,         // out row-major
        ushort* __restrict__ xfn) {       // out frag
    const int tid  = threadIdx.x;
    const int lane = tid & 63;
    const int wid  = tid >> 6;          // 0..3
    const int wr   = wid >> 1, wc = wid & 1;
    const int row0 = blockIdx.x * 128;
    const int col0 = blockIdx.y * 128;
    const int fr   = lane & 15;
    const int kq   = lane >> 4;         // 0..3

    int arow[4], bcol[4];
    #pragma unroll
    for (int i = 0; i < 4; ++i) {
        int r = row0 + wr * 64 + i * 16 + fr;
        arow[i] = r < N_NODES ? r : N_NODES - 1;   // clamp; stores guarded
    }
    #pragma unroll
    for (int j = 0; j < 4; ++j) bcol[j] = col0 + wc * 64 + j * 16 + fr;

    v4f acc[4][4] = {};
    v8s pa[2][4], pb[2][4];

    #define PF(kt, par) do {                                                       \
        const ushort* As_ = ((kt) < 8) ? Am : Ax;                                  \
        const ushort* Bs_ = ((kt) < 8) ? Bl : Br;                                  \
        const int k8_ = (((kt) & 7) << 2) + kq;                                    \
        _Pragma("unroll")                                                          \
        for (int i_ = 0; i_ < 4; ++i_)                                             \
            pa[par][i_] = *(const v8s*)(As_ + ((size_t)k8_ * NP + (unsigned)arow[i_]) * 8); \
        _Pragma("unroll")                                                          \
        for (int j_ = 0; j_ < 4; ++j_)                                             \
            pb[par][j_] = *(const v8s*)(Bs_ + (((size_t)k8_ << 8) + (unsigned)bcol[j_]) * 8); \
    } while (0)

    PF(0, 0);
    PF(1, 1);
    #pragma unroll
    for (int kt = 0; kt < 16; ++kt) {
        const int par = kt & 1;
        #pragma unroll
        for (int i = 0; i < 4; ++i)
            #pragma unroll
            for (int j = 0; j < 4; ++j)
                acc[i][j] = __builtin_amdgcn_mfma_f32_16x16x32_bf16(pa[par][i], pb[par][j], acc[i][j], 0, 0, 0);
        if (kt < 14) PF(kt + 2, par);   // scheduler hoists: depth-2 in-flight
    }
    #undef PF

    // epilogue: C/D layout col=lane&15, row=(lane>>4)*4+reg; dual store
    const int orow = (lane >> 4) * 4;
    const int ocol = lane & 15;
    #pragma unroll
    for (int j = 0; j < 4; ++j) {
        int colg = col0 + wc * 64 + j * 16 + ocol;
        float bv = bias[colg];
        size_t fbase = ((size_t)(colg >> 3) * NP) * 8 + (colg & 7);
        #pragma unroll
        for (int i = 0; i < 4; ++i) {
            int rbase = row0 + wr * 64 + i * 16 + orow;
            #pragma unroll
            for (int r = 0; r < 4; ++r) {
                int row = rbase + r;
                if (row < N_NODES) {
                    float v = fmaxf(acc[i][j][r] + bv, 0.0f)
                            + bf2f(xrow[(size_t)row * FEAT + colg]);
                    ushort bb = f2bf(v);
                    xbn[(size_t)row * FEAT + colg] = bb;
                    xfn[fbase + (size_t)row * 8]   = bb;
                }
            }
        }
    }
}

// ---- per-graph per-feature online softmax aggregation (bf16 input) ----
__global__ __launch_bounds__(256) void smax_kernel(const ushort* __restrict__ xb,
                                                   const unsigned* __restrict__ gs,
                                                   const unsigned* __restrict__ ge,
                                                   const float* __restrict__ t,
                                                   float* __restrict__ out) {
    int g = blockIdx.x;
    int f = threadIdx.x;
    unsigned s = gs[g], e = ge[g];
    float tv = t[0];
    float m = -INFINITY, den = 0.f, acc = 0.f;
    if (s < e) {
        for (unsigned n = s; n < e; ++n) {
            float xv = bf2f(xb[(size_t)n * FEAT + f]);
            float sc = tv * xv;
            float mn = fmaxf(m, sc);
            float scale = expf(m - mn);     // 0 on first iter (m = -inf)
            float w = expf(sc - mn);
            den = den * scale + w;
            acc = acc * scale + w * xv;
            m = mn;
        }
        out[(size_t)g * FEAT + f] = acc / fmaxf(den, 1e-16f);
    } else {
        out[(size_t)g * FEAT + f] = 0.f;   // empty segment -> 0 per reference
    }
}

extern "C" void kernel_launch(void* const* d_in, const int* in_sizes, int n_in,
                              void* d_out, int out_size, void* d_ws, size_t ws_size,
                              hipStream_t stream) {
    const float* x     = (const float*)d_in[0];
    const int*   ei    = (const int*)d_in[1];    // [2, E]: row0=src, row1=dst
    const int*   batch = (const int*)d_in[2];
    const float* Wl    = (const float*)d_in[3];  // [L, F, F]
    const float* bl    = (const float*)d_in[4];  // [L, F]
    const float* Wr    = (const float*)d_in[5];  // [L, F, F]
    const float* t     = (const float*)d_in[6];  // [1]
    float* out = (float*)d_out;

    const size_t NF2  = (size_t)N_NODES * FEAT * 2;   // row-major bf16 buffer
    const size_t NPF2 = (size_t)NP * FEAT * 2;        // frag-layout bf16 buffer
    const size_t WSZ  = (size_t)N_LAYERS * FEAT * FEAT * 2;

    char* ws = (char*)d_ws;
    size_t off = 0;
    ushort* xb0   = (ushort*)(ws + off); off += NF2;
    ushort* xb1   = (ushort*)(ws + off); off += NF2;
    ushort* xf0   = (ushort*)(ws + off); off += NPF2;
    ushort* xf1   = (ushort*)(ws + off); off += NPF2;
    ushort* meanf = (ushort*)(ws + off); off += NPF2;
    ushort* wlb   = (ushort*)(ws + off); off += WSZ;
    ushort* wrb   = (ushort*)(ws + off); off += WSZ;
    unsigned* degu   = (unsigned*)(ws + off); off += (size_t)N_NODES * 4;
    unsigned* excl   = (unsigned*)(ws + off); off += (size_t)N_NODES * 4;
    unsigned* bsum   = (unsigned*)(ws + off); off += 128 * 4;
    unsigned* rowptr = (unsigned*)(ws + off); off += (size_t)(N_NODES + 1) * 4;
    unsigned* cursor = (unsigned*)(ws + off); off += (size_t)N_NODES * 4;
    unsigned* col    = (unsigned*)(ws + off); off += (size_t)N_EDGES * 4;
    unsigned* gs     = (unsigned*)(ws + off); off += (size_t)N_GRAPHS * 4;
    unsigned* ge     = (unsigned*)(ws + off); off += (size_t)N_GRAPHS * 4;

    hipMemsetAsync(degu, 0, (size_t)N_NODES * 4, stream);
    hipMemsetAsync(gs, 0xFF, (size_t)N_GRAPHS * 4, stream);
    hipMemsetAsync(ge, 0, (size_t)N_GRAPHS * 4, stream);

    init_kernel<<<(N_NODES * FEAT / 4 + 255) / 256, 256, 0, stream>>>(x, xb0, xf0);
    wconv_kernel<<<(N_LAYERS * FEAT * FEAT / 4 + 255) / 256, 256, 0, stream>>>(Wl, Wr, wlb, wrb);

    // CSR build
    const int NB_SCAN = (N_NODES + SCAN_B - 1) / SCAN_B;   // 98
    hist_kernel<<<(N_EDGES + 255) / 256, 256, 0, stream>>>(ei + N_EDGES, degu);
    scan_blocks<<<NB_SCAN, SCAN_B, 0, stream>>>(degu, excl, bsum);
    scan_tops<<<1, 1, 0, stream>>>(bsum, NB_SCAN);
    finalize_rowptr<<<(N_NODES + 256) / 256, 256, 0, stream>>>(excl, bsum, rowptr, cursor);
    scatter_kernel<<<(N_EDGES + 255) / 256, 256, 0, stream>>>(ei, cursor, col);

    bounds_kernel<<<(N_NODES + 255) / 256, 256, 0, stream>>>(batch, gs, ge);

    ushort* curb = xb0; ushort* nxtb = xb1;
    ushort* curf = xf0; ushort* nxtf = xf1;
    for (int l = 0; l < N_LAYERS; ++l) {
        agg_csr<<<(N_NODES + 3) / 4, 256, 0, stream>>>(rowptr, col, curb, meanf);
        gemm_kernel<<<dim3((N_NODES + 127) / 128, 2), 256, 0, stream>>>(
            meanf, curf, curb,
            wlb + (size_t)l * FEAT * FEAT, wrb + (size_t)l * FEAT * FEAT,
            bl + (size_t)l * FEAT, nxtb, nxtf);
        ushort* tb = curb; curb = nxtb; nxtb = tb;
        ushort* tf = curf; curf = nxtf; nxtf = tf;
    }

    smax_kernel<<<N_GRAPHS, 256, 0, stream>>>(curb, gs, ge, t, out);
}

// Round 8
// 931.438 us; speedup vs baseline: 1.5747x; 1.5747x over previous
//
#include <hip/hip_runtime.h>
#include <hip/hip_bf16.h>

#define N_NODES  100000
#define N_EDGES  300000
#define FEAT     256
#define N_GRAPHS 500
#define N_LAYERS 6
#define SCAN_B   1024

typedef __attribute__((ext_vector_type(8))) short v8s;   // 8 x bf16 bits (4 VGPRs)
typedef __attribute__((ext_vector_type(4))) float v4f;   // MFMA accumulator

__device__ __forceinline__ unsigned short f2bf(float f) {
    unsigned u = __float_as_uint(f);
    unsigned r = u + 0x7fffu + ((u >> 16) & 1u);   // RNE
    return (unsigned short)(r >> 16);
}
__device__ __forceinline__ float bf2f(unsigned short b) {
    return __uint_as_float(((unsigned)b) << 16);
}

__device__ __forceinline__ void gload16(const ushort* g, ushort* l) {
    __builtin_amdgcn_global_load_lds((const __attribute__((address_space(1))) void*)g,
                                     (__attribute__((address_space(3))) void*)l,
                                     16, 0, 0);
}

// ---- init: x (f32) -> xb (bf16) ----
__global__ __launch_bounds__(256) void init_kernel(const float* __restrict__ x,
                                                   ushort* __restrict__ xb) {
    int i = blockIdx.x * 256 + threadIdx.x;           // per 4 elements
    if ((size_t)i * 4 >= (size_t)N_NODES * FEAT) return;
    float4 v = ((const float4*)x)[i];
    ((ushort4*)xb)[i] = make_ushort4(f2bf(v.x), f2bf(v.y), f2bf(v.z), f2bf(v.w));
}

// ---- weights f32 -> bf16, all layers at once ----
__global__ __launch_bounds__(256) void wconv_kernel(const float* __restrict__ Wl,
                                                    const float* __restrict__ Wr,
                                                    ushort* __restrict__ wlb,
                                                    ushort* __restrict__ wrb) {
    int i = blockIdx.x * 256 + threadIdx.x;           // per 4 elements
    if ((size_t)i * 4 >= (size_t)N_LAYERS * FEAT * FEAT) return;
    float4 a = ((const float4*)Wl)[i];
    float4 b = ((const float4*)Wr)[i];
    ((ushort4*)wlb)[i] = make_ushort4(f2bf(a.x), f2bf(a.y), f2bf(a.z), f2bf(a.w));
    ((ushort4*)wrb)[i] = make_ushort4(f2bf(b.x), f2bf(b.y), f2bf(b.z), f2bf(b.w));
}

// ================= CSR construction (counting sort by dst) =================

__global__ __launch_bounds__(256) void hist_kernel(const int* __restrict__ dst,
                                                   unsigned* __restrict__ degu) {
    int e = blockIdx.x * 256 + threadIdx.x;
    if (e < N_EDGES) atomicAdd(&degu[dst[e]], 1u);
}

__global__ __launch_bounds__(SCAN_B) void scan_blocks(const unsigned* __restrict__ degu,
                                                      unsigned* __restrict__ excl,
                                                      unsigned* __restrict__ bsum) {
    __shared__ unsigned tmp[SCAN_B];
    int i = blockIdx.x * SCAN_B + threadIdx.x;
    unsigned v = (i < N_NODES) ? degu[i] : 0u;
    tmp[threadIdx.x] = v;
    __syncthreads();
    for (int off = 1; off < SCAN_B; off <<= 1) {
        unsigned add = (threadIdx.x >= off) ? tmp[threadIdx.x - off] : 0u;
        __syncthreads();
        tmp[threadIdx.x] += add;
        __syncthreads();
    }
    if (i < N_NODES) excl[i] = tmp[threadIdx.x] - v;
    if (threadIdx.x == SCAN_B - 1) bsum[blockIdx.x] = tmp[SCAN_B - 1];
}

__global__ void scan_tops(unsigned* __restrict__ bsum, int nb) {
    unsigned run = 0;
    for (int b = 0; b < nb; ++b) { unsigned t = bsum[b]; bsum[b] = run; run += t; }
}

__global__ __launch_bounds__(256) void finalize_rowptr(const unsigned* __restrict__ excl,
                                                       const unsigned* __restrict__ bsum,
                                                       unsigned* __restrict__ rowptr,
                                                       unsigned* __restrict__ cursor) {
    int i = blockIdx.x * 256 + threadIdx.x;
    if (i < N_NODES) {
        unsigned v = excl[i] + bsum[i / SCAN_B];
        rowptr[i] = v;
        cursor[i] = v;
    }
    if (i == N_NODES) rowptr[N_NODES] = N_EDGES;
}

__global__ __launch_bounds__(256) void scatter_kernel(const int* __restrict__ ei,
                                                      unsigned* __restrict__ cursor,
                                                      unsigned* __restrict__ col) {
    int e = blockIdx.x * 256 + threadIdx.x;
    if (e >= N_EDGES) return;
    int d = ei[N_EDGES + e];
    unsigned p = atomicAdd(&cursor[d], 1u);
    col[p] = (unsigned)ei[e];
}

// ---- per-graph [start,end) bounds from sorted batch: boundary detection ----
__global__ __launch_bounds__(256) void bounds_kernel(const int* __restrict__ batch,
                                                     unsigned* __restrict__ gs,
                                                     unsigned* __restrict__ ge) {
    int i = blockIdx.x * 256 + threadIdx.x;
    if (i >= N_NODES) return;
    int g = batch[i];
    int gp = (i == 0) ? -1 : batch[i - 1];
    if (g != gp) gs[g] = (unsigned)i;
    int gn = (i == N_NODES - 1) ? -1 : batch[i + 1];
    if (g != gn) ge[g] = (unsigned)(i + 1);
}

// ---- CSR mean-aggregate: one wave per node, 4 feats/lane, no atomics ----
__global__ __launch_bounds__(256) void agg_csr(const unsigned* __restrict__ rowptr,
                                               const unsigned* __restrict__ col,
                                               const ushort* __restrict__ xb,
                                               ushort* __restrict__ meanb) {
    int node = blockIdx.x * 4 + (threadIdx.x >> 6);
    int lane = threadIdx.x & 63;
    if (node >= N_NODES) return;
    unsigned s = rowptr[node], e = rowptr[node + 1];
    float a0 = 0.f, a1 = 0.f, a2 = 0.f, a3 = 0.f;
    for (unsigned j = s; j < e; ++j) {
        unsigned src = col[j];
        ushort4 v = *(const ushort4*)(xb + (size_t)src * FEAT + lane * 4);
        a0 += bf2f(v.x); a1 += bf2f(v.y); a2 += bf2f(v.z); a3 += bf2f(v.w);
    }
    float r = 1.0f / fmaxf((float)(e - s), 1.0f);
    ushort4 o = make_ushort4(f2bf(a0 * r), f2bf(a1 * r), f2bf(a2 * r), f2bf(a3 * r));
    *(ushort4*)(meanb + (size_t)node * FEAT + lane * 4) = o;
}

// ============================================================================
// Fused GEMM: xbn = bf16( relu([meanb|x] @ [Wl|Wr]^T + bl) + x )
// BM=128, BN=256, BK=32, 8 waves (2x4 of 64x64).
// ONE-barrier-per-phase counted pipeline (T3+T4+T5): 3-buffer LDS ring (72 KB,
// 2 blocks/CU), stage tile t+2 inside phase t, vmcnt(3) waits only on loads
// issued two phases earlier, setprio around the MFMA cluster.
// LDS: 2 rows (64B) per 128B line, XOR swizzle byte ^= (line&7)<<4; linear
// LDS dest + inverse-swizzled GLOBAL source (rule 21). Verified in R4.
// ============================================================================
#define ATILE 4096   // ushorts: 128 rows x 32 elems = 8 KB
#define BTILE 8192   // ushorts: 256 rows x 32 elems = 16 KB

__global__ __launch_bounds__(512) void gemm_kernel(const ushort* __restrict__ A0,   // meanb
                                                   const ushort* __restrict__ A1,   // x (bf16), also residual
                                                   const ushort* __restrict__ B0,   // Wl slice [256][256]
                                                   const ushort* __restrict__ B1,   // Wr slice
                                                   const float* __restrict__ bias,  // bl slice [256]
                                                   ushort* __restrict__ xbn) {      // next-layer x
    __shared__ ushort As[3][ATILE];   // 3 x 8 KB
    __shared__ ushort Bs[3][BTILE];   // 3 x 16 KB   (72 KB total)

    const int tid  = threadIdx.x;
    const int lane = tid & 63;
    const int wid  = tid >> 6;          // 0..7
    const int wr   = wid >> 2;          // 0..1  (row half of 128)
    const int wc   = wid & 3;           // 0..3  (col quarter of 256)
    const int row0 = blockIdx.x * 128;

    v4f acc[4][4] = {};

    const int fr  = lane & 15;
    const int cbk = (lane >> 4) << 4;   // frag byte col within 64B row: 0,16,32,48

    // ---- staging address precompute (kt-invariant parts) ----
    const int pA  = tid >> 3;
    const int w0A = ((tid & 7) ^ (pA & 7)) << 4;
    int rA = row0 + 2 * pA + (w0A >> 6);
    rA = rA < N_NODES ? rA : N_NODES - 1;
    const int cbA = w0A & 63;
    const int pB0  = tid >> 3;
    const int w0B0 = ((tid & 7) ^ (pB0 & 7)) << 4;
    const int rB0  = 2 * pB0 + (w0B0 >> 6);
    const int cbB0 = w0B0 & 63;
    const int c1   = tid + 512;
    const int pB1  = c1 >> 3;
    const int w0B1 = ((c1 & 7) ^ (pB1 & 7)) << 4;
    const int rB1  = 2 * pB1 + (w0B1 >> 6);
    const int cbB1 = w0B1 & 63;

    #define STAGE(buf, kt) do {                                                   \
        const ushort* Asrc = ((kt) < 8) ? A0 : A1;                                \
        const ushort* Bsrc = ((kt) < 8) ? B0 : B1;                                \
        const int kb = ((kt) & 7) * 32;                                           \
        gload16(Asrc + (size_t)rA  * FEAT + kb + (cbA  >> 1), &As[buf][tid * 8]); \
        gload16(Bsrc + (size_t)rB0 * FEAT + kb + (cbB0 >> 1), &Bs[buf][tid * 8]); \
        gload16(Bsrc + (size_t)rB1 * FEAT + kb + (cbB1 >> 1), &Bs[buf][(size_t)c1 * 8]); \
    } while (0)

    #define FRAG(basePtr, row) \
        (*(const v8s*)((const char*)(basePtr) + (((row) >> 1) * 128 + \
            ((((row) & 1) << 6) + cbk) ^ ((((row) >> 1) & 7) << 4))))

    #define DSREAD(buf) do {                                                      \
        _Pragma("unroll")                                                         \
        for (int i = 0; i < 4; ++i) a[i] = FRAG(As[buf], wr * 64 + i * 16 + fr);  \
        _Pragma("unroll")                                                         \
        for (int j = 0; j < 4; ++j) b[j] = FRAG(Bs[buf], wc * 64 + j * 16 + fr);  \
    } while (0)

    #define MFMA16() do {                                                         \
        _Pragma("unroll")                                                         \
        for (int i = 0; i < 4; ++i)                                               \
            _Pragma("unroll")                                                     \
            for (int j = 0; j < 4; ++j)                                           \
                acc[i][j] = __builtin_amdgcn_mfma_f32_16x16x32_bf16(a[i], b[j], acc[i][j], 0, 0, 0); \
    } while (0)

    STAGE(0, 0);
    STAGE(1, 1);
    int bufC = 0, bufS = 2;
    v8s a[4], b[4];
    #pragma unroll 1
    for (int kt = 0; kt < 15; ++kt) {
        // tile kt's 3 loads (issued 2 phases ago) done; tile kt+1's may remain
        asm volatile("s_waitcnt vmcnt(3)" ::: "memory");
        __builtin_amdgcn_s_barrier();          // all waves: tile kt landed; buf[bufS] free
        __builtin_amdgcn_sched_barrier(0);
        if (kt <= 13) STAGE(bufS, kt + 2);     // in flight across the next 2 phases
        DSREAD(bufC);
        asm volatile("s_waitcnt lgkmcnt(0)" ::: "memory");
        __builtin_amdgcn_sched_barrier(0);
        __builtin_amdgcn_s_setprio(1);
        MFMA16();
        __builtin_amdgcn_s_setprio(0);
        bufC = (bufC == 2) ? 0 : bufC + 1;
        bufS = (bufS == 2) ? 0 : bufS + 1;
    }
    // final phase: tile 15
    asm volatile("s_waitcnt vmcnt(0)" ::: "memory");
    __builtin_amdgcn_s_barrier();
    __builtin_amdgcn_sched_barrier(0);
    DSREAD(bufC);
    asm volatile("s_waitcnt lgkmcnt(0)" ::: "memory");
    __builtin_amdgcn_sched_barrier(0);
    MFMA16();

    // epilogue: C/D layout col=lane&15, row=(lane>>4)*4+reg
    const int orow = (lane >> 4) * 4;
    const int ocol = lane & 15;
    #pragma unroll
    for (int j = 0; j < 4; ++j) {
        int colg = wc * 64 + j * 16 + ocol;
        float bv = bias[colg];
        #pragma unroll
        for (int i = 0; i < 4; ++i) {
            int rbase = row0 + wr * 64 + i * 16 + orow;
            #pragma unroll
            for (int r = 0; r < 4; ++r) {
                int row = rbase + r;
                if (row < N_NODES) {
                    size_t idx = (size_t)row * FEAT + colg;
                    float v = fmaxf(acc[i][j][r] + bv, 0.0f) + bf2f(A1[idx]);
                    xbn[idx] = f2bf(v);
                }
            }
        }
    }
    #undef STAGE
    #undef FRAG
    #undef DSREAD
    #undef MFMA16
}

// ---- per-graph per-feature online softmax aggregation (bf16 input) ----
__global__ __launch_bounds__(256) void smax_kernel(const ushort* __restrict__ xb,
                                                   const unsigned* __restrict__ gs,
                                                   const unsigned* __restrict__ ge,
                                                   const float* __restrict__ t,
                                                   float* __restrict__ out) {
    int g = blockIdx.x;
    int f = threadIdx.x;
    unsigned s = gs[g], e = ge[g];
    float tv = t[0];
    float m = -INFINITY, den = 0.f, acc = 0.f;
    if (s < e) {
        for (unsigned n = s; n < e; ++n) {
            float xv = bf2f(xb[(size_t)n * FEAT + f]);
            float sc = tv * xv;
            float mn = fmaxf(m, sc);
            float scale = expf(m - mn);     // 0 on first iter (m = -inf)
            float w = expf(sc - mn);
            den = den * scale + w;
            acc = acc * scale + w * xv;
            m = mn;
        }
        out[(size_t)g * FEAT + f] = acc / fmaxf(den, 1e-16f);
    } else {
        out[(size_t)g * FEAT + f] = 0.f;   // empty segment -> 0 per reference
    }
}

extern "C" void kernel_launch(void* const* d_in, const int* in_sizes, int n_in,
                              void* d_out, int out_size, void* d_ws, size_t ws_size,
                              hipStream_t stream) {
    const float* x     = (const float*)d_in[0];
    const int*   ei    = (const int*)d_in[1];    // [2, E]: row0=src, row1=dst
    const int*   batch = (const int*)d_in[2];
    const float* Wl    = (const float*)d_in[3];  // [L, F, F]
    const float* bl    = (const float*)d_in[4];  // [L, F]
    const float* Wr    = (const float*)d_in[5];  // [L, F, F]
    const float* t     = (const float*)d_in[6];  // [1]
    float* out = (float*)d_out;

    const size_t NF2 = (size_t)N_NODES * FEAT * 2;   // 51,200,000
    const size_t WSZ = (size_t)N_LAYERS * FEAT * FEAT * 2;

    char* ws = (char*)d_ws;
    size_t off = 0;
    ushort* xb0   = (ushort*)(ws + off); off += NF2;
    ushort* xb1   = (ushort*)(ws + off); off += NF2;
    ushort* meanb = (ushort*)(ws + off); off += NF2;
    ushort* wlb   = (ushort*)(ws + off); off += WSZ;
    ushort* wrb   = (ushort*)(ws + off); off += WSZ;
    unsigned* degu   = (unsigned*)(ws + off); off += (size_t)N_NODES * 4;
    unsigned* excl   = (unsigned*)(ws + off); off += (size_t)N_NODES * 4;
    unsigned* bsum   = (unsigned*)(ws + off); off += 128 * 4;
    unsigned* rowptr = (unsigned*)(ws + off); off += (size_t)(N_NODES + 1) * 4;
    unsigned* cursor = (unsigned*)(ws + off); off += (size_t)N_NODES * 4;
    unsigned* col    = (unsigned*)(ws + off); off += (size_t)N_EDGES * 4;
    unsigned* gs     = (unsigned*)(ws + off); off += (size_t)N_GRAPHS * 4;
    unsigned* ge     = (unsigned*)(ws + off); off += (size_t)N_GRAPHS * 4;

    hipMemsetAsync(degu, 0, (size_t)N_NODES * 4, stream);
    hipMemsetAsync(gs, 0xFF, (size_t)N_GRAPHS * 4, stream);
    hipMemsetAsync(ge, 0, (size_t)N_GRAPHS * 4, stream);

    init_kernel<<<(N_NODES * FEAT / 4 + 255) / 256, 256, 0, stream>>>(x, xb0);
    wconv_kernel<<<(N_LAYERS * FEAT * FEAT / 4 + 255) / 256, 256, 0, stream>>>(Wl, Wr, wlb, wrb);

    // CSR build
    const int NB_SCAN = (N_NODES + SCAN_B - 1) / SCAN_B;   // 98
    hist_kernel<<<(N_EDGES + 255) / 256, 256, 0, stream>>>(ei + N_EDGES, degu);
    scan_blocks<<<NB_SCAN, SCAN_B, 0, stream>>>(degu, excl, bsum);
    scan_tops<<<1, 1, 0, stream>>>(bsum, NB_SCAN);
    finalize_rowptr<<<(N_NODES + 256) / 256, 256, 0, stream>>>(excl, bsum, rowptr, cursor);
    scatter_kernel<<<(N_EDGES + 255) / 256, 256, 0, stream>>>(ei, cursor, col);

    bounds_kernel<<<(N_NODES + 255) / 256, 256, 0, stream>>>(batch, gs, ge);

    ushort* cur = xb0;
    ushort* nxt = xb1;
    for (int l = 0; l < N_LAYERS; ++l) {
        agg_csr<<<(N_NODES + 3) / 4, 256, 0, stream>>>(rowptr, col, cur, meanb);
        gemm_kernel<<<dim3((N_NODES + 127) / 128), 512, 0, stream>>>(
            meanb, cur,
            wlb + (size_t)l * FEAT * FEAT, wrb + (size_t)l * FEAT * FEAT,
            bl + (size_t)l * FEAT, nxt);
        ushort* tmp = cur; cur = nxt; nxt = tmp;
    }

    smax_kernel<<<N_GRAPHS, 256, 0, stream>>>(cur, gs, ge, t, out);
}

// Round 9
// 727.591 us; speedup vs baseline: 2.0159x; 1.2802x over previous
//
#include <hip/hip_runtime.h>
#include <hip/hip_bf16.h>

#define N_NODES  100000
#define N_EDGES  300000
#define FEAT     256
#define N_GRAPHS 500
#define N_LAYERS 6
#define SCAN_B   1024

typedef __attribute__((ext_vector_type(8))) short v8s;   // 8 x bf16 bits (4 VGPRs)
typedef __attribute__((ext_vector_type(4))) float v4f;   // MFMA accumulator

__device__ __forceinline__ unsigned short f2bf(float f) {
    unsigned u = __float_as_uint(f);
    unsigned r = u + 0x7fffu + ((u >> 16) & 1u);   // RNE
    return (unsigned short)(r >> 16);
}
__device__ __forceinline__ float bf2f(unsigned short b) {
    return __uint_as_float(((unsigned)b) << 16);
}

__device__ __forceinline__ void gload16(const ushort* g, ushort* l) {
    __builtin_amdgcn_global_load_lds((const __attribute__((address_space(1))) void*)g,
                                     (__attribute__((address_space(3))) void*)l,
                                     16, 0, 0);
}

// ---- init: x (f32) -> xb (bf16) ----
__global__ __launch_bounds__(256) void init_kernel(const float* __restrict__ x,
                                                   ushort* __restrict__ xb) {
    int i = blockIdx.x * 256 + threadIdx.x;           // per 4 elements
    if ((size_t)i * 4 >= (size_t)N_NODES * FEAT) return;
    float4 v = ((const float4*)x)[i];
    ((ushort4*)xb)[i] = make_ushort4(f2bf(v.x), f2bf(v.y), f2bf(v.z), f2bf(v.w));
}

// ---- weights f32 -> bf16, all layers at once ----
__global__ __launch_bounds__(256) void wconv_kernel(const float* __restrict__ Wl,
                                                    const float* __restrict__ Wr,
                                                    ushort* __restrict__ wlb,
                                                    ushort* __restrict__ wrb) {
    int i = blockIdx.x * 256 + threadIdx.x;           // per 4 elements
    if ((size_t)i * 4 >= (size_t)N_LAYERS * FEAT * FEAT) return;
    float4 a = ((const float4*)Wl)[i];
    float4 b = ((const float4*)Wr)[i];
    ((ushort4*)wlb)[i] = make_ushort4(f2bf(a.x), f2bf(a.y), f2bf(a.z), f2bf(a.w));
    ((ushort4*)wrb)[i] = make_ushort4(f2bf(b.x), f2bf(b.y), f2bf(b.z), f2bf(b.w));
}

// ================= CSR construction (counting sort by dst) =================

__global__ __launch_bounds__(256) void hist_kernel(const int* __restrict__ dst,
                                                   unsigned* __restrict__ degu) {
    int e = blockIdx.x * 256 + threadIdx.x;
    if (e < N_EDGES) atomicAdd(&degu[dst[e]], 1u);
}

__global__ __launch_bounds__(SCAN_B) void scan_blocks(const unsigned* __restrict__ degu,
                                                      unsigned* __restrict__ excl,
                                                      unsigned* __restrict__ bsum) {
    __shared__ unsigned tmp[SCAN_B];
    int i = blockIdx.x * SCAN_B + threadIdx.x;
    unsigned v = (i < N_NODES) ? degu[i] : 0u;
    tmp[threadIdx.x] = v;
    __syncthreads();
    for (int off = 1; off < SCAN_B; off <<= 1) {
        unsigned add = (threadIdx.x >= off) ? tmp[threadIdx.x - off] : 0u;
        __syncthreads();
        tmp[threadIdx.x] += add;
        __syncthreads();
    }
    if (i < N_NODES) excl[i] = tmp[threadIdx.x] - v;
    if (threadIdx.x == SCAN_B - 1) bsum[blockIdx.x] = tmp[SCAN_B - 1];
}

__global__ void scan_tops(unsigned* __restrict__ bsum, int nb) {
    unsigned run = 0;
    for (int b = 0; b < nb; ++b) { unsigned t = bsum[b]; bsum[b] = run; run += t; }
}

__global__ __launch_bounds__(256) void finalize_rowptr(const unsigned* __restrict__ excl,
                                                       const unsigned* __restrict__ bsum,
                                                       unsigned* __restrict__ rowptr,
                                                       unsigned* __restrict__ cursor) {
    int i = blockIdx.x * 256 + threadIdx.x;
    if (i < N_NODES) {
        unsigned v = excl[i] + bsum[i / SCAN_B];
        rowptr[i] = v;
        cursor[i] = v;
    }
    if (i == N_NODES) rowptr[N_NODES] = N_EDGES;
}

__global__ __launch_bounds__(256) void scatter_kernel(const int* __restrict__ ei,
                                                      unsigned* __restrict__ cursor,
                                                      unsigned* __restrict__ col) {
    int e = blockIdx.x * 256 + threadIdx.x;
    if (e >= N_EDGES) return;
    int d = ei[N_EDGES + e];
    unsigned p = atomicAdd(&cursor[d], 1u);
    col[p] = (unsigned)ei[e];
}

// ---- per-graph [start,end) bounds from sorted batch: boundary detection ----
__global__ __launch_bounds__(256) void bounds_kernel(const int* __restrict__ batch,
                                                     unsigned* __restrict__ gs,
                                                     unsigned* __restrict__ ge) {
    int i = blockIdx.x * 256 + threadIdx.x;
    if (i >= N_NODES) return;
    int g = batch[i];
    int gp = (i == 0) ? -1 : batch[i - 1];
    if (g != gp) gs[g] = (unsigned)i;
    int gn = (i == N_NODES - 1) ? -1 : batch[i + 1];
    if (g != gn) ge[g] = (unsigned)(i + 1);
}

// ---- CSR mean-aggregate: one wave per node, 4 feats/lane, no atomics ----
__global__ __launch_bounds__(256) void agg_csr(const unsigned* __restrict__ rowptr,
                                               const unsigned* __restrict__ col,
                                               const ushort* __restrict__ xb,
                                               ushort* __restrict__ meanb) {
    int node = blockIdx.x * 4 + (threadIdx.x >> 6);
    int lane = threadIdx.x & 63;
    if (node >= N_NODES) return;
    unsigned s = rowptr[node], e = rowptr[node + 1];
    float a0 = 0.f, a1 = 0.f, a2 = 0.f, a3 = 0.f;
    for (unsigned j = s; j < e; ++j) {
        unsigned src = col[j];
        ushort4 v = *(const ushort4*)(xb + (size_t)src * FEAT + lane * 4);
        a0 += bf2f(v.x); a1 += bf2f(v.y); a2 += bf2f(v.z); a3 += bf2f(v.w);
    }
    float r = 1.0f / fmaxf((float)(e - s), 1.0f);
    ushort4 o = make_ushort4(f2bf(a0 * r), f2bf(a1 * r), f2bf(a2 * r), f2bf(a3 * r));
    *(ushort4*)(meanb + (size_t)node * FEAT + lane * 4) = o;
}

// ============================================================================
// Fused GEMM: xbn = bf16( relu([meanb|x] @ [Wl|Wr]^T + bl) + x )
// BM=128, BN=256, BK=32, 8 waves (2x4 of 64x64).
// One-barrier-per-phase counted pipeline (R8), PLUS coalesced epilogue:
// acc -> LDS [128][264] bf16 (pad breaks 512B-stride bank alias) -> barrier ->
// 16B ds_read / 16B global residual load / 16B store per chunk (was 128
// scalar 2B VMEM ops per thread).
// ============================================================================
#define ATILE 4096   // ushorts: 128 rows x 32 elems = 8 KB
#define BTILE 8192   // ushorts: 256 rows x 32 elems = 16 KB
#define CPAD  264    // epilogue row stride (256 + 8)

__global__ __launch_bounds__(512) void gemm_kernel(const ushort* __restrict__ A0,   // meanb
                                                   const ushort* __restrict__ A1,   // x (bf16), also residual
                                                   const ushort* __restrict__ B0,   // Wl slice [256][256]
                                                   const ushort* __restrict__ B1,   // Wr slice
                                                   const float* __restrict__ bias,  // bl slice [256]
                                                   ushort* __restrict__ xbn) {      // next-layer x
    __shared__ ushort lds[36864];                    // 72 KB
    ushort (*As)[ATILE] = (ushort(*)[ATILE])lds;                 // 3 x 8 KB
    ushort (*Bs)[BTILE] = (ushort(*)[BTILE])(lds + 3 * ATILE);   // 3 x 16 KB
    ushort* Cs = lds;                                // epilogue reuse: [128][264] = 66 KB

    const int tid  = threadIdx.x;
    const int lane = tid & 63;
    const int wid  = tid >> 6;          // 0..7
    const int wr   = wid >> 2;          // 0..1  (row half of 128)
    const int wc   = wid & 3;           // 0..3  (col quarter of 256)
    const int row0 = blockIdx.x * 128;

    v4f acc[4][4] = {};

    const int fr  = lane & 15;
    const int cbk = (lane >> 4) << 4;   // frag byte col within 64B row: 0,16,32,48

    // ---- staging address precompute (kt-invariant parts) ----
    const int pA  = tid >> 3;
    const int w0A = ((tid & 7) ^ (pA & 7)) << 4;
    int rA = row0 + 2 * pA + (w0A >> 6);
    rA = rA < N_NODES ? rA : N_NODES - 1;
    const int cbA = w0A & 63;
    const int pB0  = tid >> 3;
    const int w0B0 = ((tid & 7) ^ (pB0 & 7)) << 4;
    const int rB0  = 2 * pB0 + (w0B0 >> 6);
    const int cbB0 = w0B0 & 63;
    const int c1   = tid + 512;
    const int pB1  = c1 >> 3;
    const int w0B1 = ((c1 & 7) ^ (pB1 & 7)) << 4;
    const int rB1  = 2 * pB1 + (w0B1 >> 6);
    const int cbB1 = w0B1 & 63;

    #define STAGE(buf, kt) do {                                                   \
        const ushort* Asrc = ((kt) < 8) ? A0 : A1;                                \
        const ushort* Bsrc = ((kt) < 8) ? B0 : B1;                                \
        const int kb = ((kt) & 7) * 32;                                           \
        gload16(Asrc + (size_t)rA  * FEAT + kb + (cbA  >> 1), &As[buf][tid * 8]); \
        gload16(Bsrc + (size_t)rB0 * FEAT + kb + (cbB0 >> 1), &Bs[buf][tid * 8]); \
        gload16(Bsrc + (size_t)rB1 * FEAT + kb + (cbB1 >> 1), &Bs[buf][(size_t)c1 * 8]); \
    } while (0)

    #define FRAG(basePtr, row) \
        (*(const v8s*)((const char*)(basePtr) + (((row) >> 1) * 128 + \
            ((((row) & 1) << 6) + cbk) ^ ((((row) >> 1) & 7) << 4))))

    #define DSREAD(buf) do {                                                      \
        _Pragma("unroll")                                                         \
        for (int i = 0; i < 4; ++i) a[i] = FRAG(As[buf], wr * 64 + i * 16 + fr);  \
        _Pragma("unroll")                                                         \
        for (int j = 0; j < 4; ++j) b[j] = FRAG(Bs[buf], wc * 64 + j * 16 + fr);  \
    } while (0)

    #define MFMA16() do {                                                         \
        _Pragma("unroll")                                                         \
        for (int i = 0; i < 4; ++i)                                               \
            _Pragma("unroll")                                                     \
            for (int j = 0; j < 4; ++j)                                           \
                acc[i][j] = __builtin_amdgcn_mfma_f32_16x16x32_bf16(a[i], b[j], acc[i][j], 0, 0, 0); \
    } while (0)

    STAGE(0, 0);
    STAGE(1, 1);
    int bufC = 0, bufS = 2;
    v8s a[4], b[4];
    #pragma unroll 1
    for (int kt = 0; kt < 15; ++kt) {
        asm volatile("s_waitcnt vmcnt(3)" ::: "memory");
        __builtin_amdgcn_s_barrier();          // all waves: tile kt landed; buf[bufS] free
        __builtin_amdgcn_sched_barrier(0);
        if (kt <= 13) STAGE(bufS, kt + 2);     // in flight across the next 2 phases
        DSREAD(bufC);
        asm volatile("s_waitcnt lgkmcnt(0)" ::: "memory");
        __builtin_amdgcn_sched_barrier(0);
        __builtin_amdgcn_s_setprio(1);
        MFMA16();
        __builtin_amdgcn_s_setprio(0);
        bufC = (bufC == 2) ? 0 : bufC + 1;
        bufS = (bufS == 2) ? 0 : bufS + 1;
    }
    // final phase: tile 15
    asm volatile("s_waitcnt vmcnt(0)" ::: "memory");
    __builtin_amdgcn_s_barrier();
    __builtin_amdgcn_sched_barrier(0);
    DSREAD(bufC);
    asm volatile("s_waitcnt lgkmcnt(0)" ::: "memory");
    __builtin_amdgcn_sched_barrier(0);
    MFMA16();

    // ================= epilogue =================
    // 1) acc (+bias, relu) -> Cs[128][264] bf16
    __builtin_amdgcn_s_barrier();              // all waves done with As/Bs ring
    {
        const int orow = (lane >> 4) * 4;
        const int ocol = lane & 15;
        #pragma unroll
        for (int j = 0; j < 4; ++j) {
            int colg = wc * 64 + j * 16 + ocol;
            float bv = bias[colg];
            #pragma unroll
            for (int i = 0; i < 4; ++i) {
                int rl = wr * 64 + i * 16 + orow;
                #pragma unroll
                for (int r = 0; r < 4; ++r)
                    Cs[(rl + r) * CPAD + colg] = f2bf(fmaxf(acc[i][j][r] + bv, 0.0f));
            }
        }
    }
    __builtin_amdgcn_s_barrier();
    // 2) coalesced residual add + store: thread -> row p*64 + (tid>>3), 4 chunks
    #pragma unroll
    for (int p = 0; p < 2; ++p) {
        int rl  = p * 64 + (tid >> 3);
        int row = row0 + rl;
        #pragma unroll
        for (int it = 0; it < 4; ++it) {
            int c0 = (tid & 7) * 8 + it * 64;
            v8s y = *(const v8s*)(Cs + rl * CPAD + c0);
            if (row < N_NODES) {
                v8s xv = *(const v8s*)(A1 + (size_t)row * FEAT + c0);
                v8s o;
                #pragma unroll
                for (int k = 0; k < 8; ++k)
                    o[k] = (short)f2bf(bf2f((ushort)y[k]) + bf2f((ushort)xv[k]));
                *(v8s*)(xbn + (size_t)row * FEAT + c0) = o;
            }
        }
    }
    #undef STAGE
    #undef FRAG
    #undef DSREAD
    #undef MFMA16
}

// ---- per-graph per-feature online softmax aggregation (bf16 input) ----
__global__ __launch_bounds__(256) void smax_kernel(const ushort* __restrict__ xb,
                                                   const unsigned* __restrict__ gs,
                                                   const unsigned* __restrict__ ge,
                                                   const float* __restrict__ t,
                                                   float* __restrict__ out) {
    int g = blockIdx.x;
    int f = threadIdx.x;
    unsigned s = gs[g], e = ge[g];
    float tv = t[0];
    float m = -INFINITY, den = 0.f, acc = 0.f;
    if (s < e) {
        for (unsigned n = s; n < e; ++n) {
            float xv = bf2f(xb[(size_t)n * FEAT + f]);
            float sc = tv * xv;
            float mn = fmaxf(m, sc);
            float scale = expf(m - mn);     // 0 on first iter (m = -inf)
            float w = expf(sc - mn);
            den = den * scale + w;
            acc = acc * scale + w * xv;
            m = mn;
        }
        out[(size_t)g * FEAT + f] = acc / fmaxf(den, 1e-16f);
    } else {
        out[(size_t)g * FEAT + f] = 0.f;   // empty segment -> 0 per reference
    }
}

extern "C" void kernel_launch(void* const* d_in, const int* in_sizes, int n_in,
                              void* d_out, int out_size, void* d_ws, size_t ws_size,
                              hipStream_t stream) {
    const float* x     = (const float*)d_in[0];
    const int*   ei    = (const int*)d_in[1];    // [2, E]: row0=src, row1=dst
    const int*   batch = (const int*)d_in[2];
    const float* Wl    = (const float*)d_in[3];  // [L, F, F]
    const float* bl    = (const float*)d_in[4];  // [L, F]
    const float* Wr    = (const float*)d_in[5];  // [L, F, F]
    const float* t     = (const float*)d_in[6];  // [1]
    float* out = (float*)d_out;

    const size_t NF2 = (size_t)N_NODES * FEAT * 2;   // 51,200,000
    const size_t WSZ = (size_t)N_LAYERS * FEAT * FEAT * 2;

    char* ws = (char*)d_ws;
    size_t off = 0;
    ushort* xb0   = (ushort*)(ws + off); off += NF2;
    ushort* xb1   = (ushort*)(ws + off); off += NF2;
    ushort* meanb = (ushort*)(ws + off); off += NF2;
    ushort* wlb   = (ushort*)(ws + off); off += WSZ;
    ushort* wrb   = (ushort*)(ws + off); off += WSZ;
    unsigned* degu   = (unsigned*)(ws + off); off += (size_t)N_NODES * 4;
    unsigned* excl   = (unsigned*)(ws + off); off += (size_t)N_NODES * 4;
    unsigned* bsum   = (unsigned*)(ws + off); off += 128 * 4;
    unsigned* rowptr = (unsigned*)(ws + off); off += (size_t)(N_NODES + 1) * 4;
    unsigned* cursor = (unsigned*)(ws + off); off += (size_t)N_NODES * 4;
    unsigned* col    = (unsigned*)(ws + off); off += (size_t)N_EDGES * 4;
    unsigned* gs     = (unsigned*)(ws + off); off += (size_t)N_GRAPHS * 4;
    unsigned* ge     = (unsigned*)(ws + off); off += (size_t)N_GRAPHS * 4;

    hipMemsetAsync(degu, 0, (size_t)N_NODES * 4, stream);
    hipMemsetAsync(gs, 0xFF, (size_t)N_GRAPHS * 4, stream);
    hipMemsetAsync(ge, 0, (size_t)N_GRAPHS * 4, stream);

    init_kernel<<<(N_NODES * FEAT / 4 + 255) / 256, 256, 0, stream>>>(x, xb0);
    wconv_kernel<<<(N_LAYERS * FEAT * FEAT / 4 + 255) / 256, 256, 0, stream>>>(Wl, Wr, wlb, wrb);

    // CSR build
    const int NB_SCAN = (N_NODES + SCAN_B - 1) / SCAN_B;   // 98
    hist_kernel<<<(N_EDGES + 255) / 256, 256, 0, stream>>>(ei + N_EDGES, degu);
    scan_blocks<<<NB_SCAN, SCAN_B, 0, stream>>>(degu, excl, bsum);
    scan_tops<<<1, 1, 0, stream>>>(bsum, NB_SCAN);
    finalize_rowptr<<<(N_NODES + 256) / 256, 256, 0, stream>>>(excl, bsum, rowptr, cursor);
    scatter_kernel<<<(N_EDGES + 255) / 256, 256, 0, stream>>>(ei, cursor, col);

    bounds_kernel<<<(N_NODES + 255) / 256, 256, 0, stream>>>(batch, gs, ge);

    ushort* cur = xb0;
    ushort* nxt = xb1;
    for (int l = 0; l < N_LAYERS; ++l) {
        agg_csr<<<(N_NODES + 3) / 4, 256, 0, stream>>>(rowptr, col, cur, meanb);
        gemm_kernel<<<dim3((N_NODES + 127) / 128), 512, 0, stream>>>(
            meanb, cur,
            wlb + (size_t)l * FEAT * FEAT, wrb + (size_t)l * FEAT * FEAT,
            bl + (size_t)l * FEAT, nxt);
        ushort* tmp = cur; cur = nxt; nxt = tmp;
    }

    smax_kernel<<<N_GRAPHS, 256, 0, stream>>>(cur, gs, ge, t, out);
}

// Round 10
// 666.022 us; speedup vs baseline: 2.2022x; 1.0924x over previous
//
#include <hip/hip_runtime.h>
#include <hip/hip_bf16.h>

#define N_NODES  100000
#define N_EDGES  300000
#define FEAT     256
#define N_GRAPHS 500
#define N_LAYERS 6
#define SCAN_B   1024

typedef __attribute__((ext_vector_type(8))) short v8s;   // 8 x bf16 bits (4 VGPRs)
typedef __attribute__((ext_vector_type(4))) float v4f;   // MFMA accumulator

__device__ __forceinline__ unsigned short f2bf(float f) {
    unsigned u = __float_as_uint(f);
    unsigned r = u + 0x7fffu + ((u >> 16) & 1u);   // RNE
    return (unsigned short)(r >> 16);
}
__device__ __forceinline__ float bf2f(unsigned short b) {
    return __uint_as_float(((unsigned)b) << 16);
}

__device__ __forceinline__ void gload16(const ushort* g, ushort* l) {
    __builtin_amdgcn_global_load_lds((const __attribute__((address_space(1))) void*)g,
                                     (__attribute__((address_space(3))) void*)l,
                                     16, 0, 0);
}

// ---- init: x (f32) -> xb (bf16) ----
__global__ __launch_bounds__(256) void init_kernel(const float* __restrict__ x,
                                                   ushort* __restrict__ xb) {
    int i = blockIdx.x * 256 + threadIdx.x;           // per 4 elements
    if ((size_t)i * 4 >= (size_t)N_NODES * FEAT) return;
    float4 v = ((const float4*)x)[i];
    ((ushort4*)xb)[i] = make_ushort4(f2bf(v.x), f2bf(v.y), f2bf(v.z), f2bf(v.w));
}

// ---- weights f32 -> bf16, all layers at once ----
__global__ __launch_bounds__(256) void wconv_kernel(const float* __restrict__ Wl,
                                                    const float* __restrict__ Wr,
                                                    ushort* __restrict__ wlb,
                                                    ushort* __restrict__ wrb) {
    int i = blockIdx.x * 256 + threadIdx.x;           // per 4 elements
    if ((size_t)i * 4 >= (size_t)N_LAYERS * FEAT * FEAT) return;
    float4 a = ((const float4*)Wl)[i];
    float4 b = ((const float4*)Wr)[i];
    ((ushort4*)wlb)[i] = make_ushort4(f2bf(a.x), f2bf(a.y), f2bf(a.z), f2bf(a.w));
    ((ushort4*)wrb)[i] = make_ushort4(f2bf(b.x), f2bf(b.y), f2bf(b.z), f2bf(b.w));
}

// ================= CSR construction (counting sort by dst) =================

__global__ __launch_bounds__(256) void hist_kernel(const int* __restrict__ dst,
                                                   unsigned* __restrict__ degu) {
    int e = blockIdx.x * 256 + threadIdx.x;
    if (e < N_EDGES) atomicAdd(&degu[dst[e]], 1u);
}

__global__ __launch_bounds__(SCAN_B) void scan_blocks(const unsigned* __restrict__ degu,
                                                      unsigned* __restrict__ excl,
                                                      unsigned* __restrict__ bsum) {
    __shared__ unsigned tmp[SCAN_B];
    int i = blockIdx.x * SCAN_B + threadIdx.x;
    unsigned v = (i < N_NODES) ? degu[i] : 0u;
    tmp[threadIdx.x] = v;
    __syncthreads();
    for (int off = 1; off < SCAN_B; off <<= 1) {
        unsigned add = (threadIdx.x >= off) ? tmp[threadIdx.x - off] : 0u;
        __syncthreads();
        tmp[threadIdx.x] += add;
        __syncthreads();
    }
    if (i < N_NODES) excl[i] = tmp[threadIdx.x] - v;
    if (threadIdx.x == SCAN_B - 1) bsum[blockIdx.x] = tmp[SCAN_B - 1];
}

__global__ void scan_tops(unsigned* __restrict__ bsum, int nb) {
    unsigned run = 0;
    for (int b = 0; b < nb; ++b) { unsigned t = bsum[b]; bsum[b] = run; run += t; }
}

__global__ __launch_bounds__(256) void finalize_rowptr(const unsigned* __restrict__ excl,
                                                       const unsigned* __restrict__ bsum,
                                                       unsigned* __restrict__ rowptr,
                                                       unsigned* __restrict__ cursor) {
    int i = blockIdx.x * 256 + threadIdx.x;
    if (i < N_NODES) {
        unsigned v = excl[i] + bsum[i / SCAN_B];
        rowptr[i] = v;
        cursor[i] = v;
    }
    if (i == N_NODES) rowptr[N_NODES] = N_EDGES;
}

__global__ __launch_bounds__(256) void scatter_kernel(const int* __restrict__ ei,
                                                      unsigned* __restrict__ cursor,
                                                      unsigned* __restrict__ col) {
    int e = blockIdx.x * 256 + threadIdx.x;
    if (e >= N_EDGES) return;
    int d = ei[N_EDGES + e];
    unsigned p = atomicAdd(&cursor[d], 1u);
    col[p] = (unsigned)ei[e];
}

// ---- per-graph [start,end) bounds from sorted batch: boundary detection ----
__global__ __launch_bounds__(256) void bounds_kernel(const int* __restrict__ batch,
                                                     unsigned* __restrict__ gs,
                                                     unsigned* __restrict__ ge) {
    int i = blockIdx.x * 256 + threadIdx.x;
    if (i >= N_NODES) return;
    int g = batch[i];
    int gp = (i == 0) ? -1 : batch[i - 1];
    if (g != gp) gs[g] = (unsigned)i;
    int gn = (i == N_NODES - 1) ? -1 : batch[i + 1];
    if (g != gn) ge[g] = (unsigned)(i + 1);
}

// ---- CSR mean-aggregate: one wave per node, 4 feats/lane, no atomics ----
__global__ __launch_bounds__(256) void agg_csr(const unsigned* __restrict__ rowptr,
                                               const unsigned* __restrict__ col,
                                               const ushort* __restrict__ xb,
                                               ushort* __restrict__ meanb) {
    int node = blockIdx.x * 4 + (threadIdx.x >> 6);
    int lane = threadIdx.x & 63;
    if (node >= N_NODES) return;
    unsigned s = rowptr[node], e = rowptr[node + 1];
    float a0 = 0.f, a1 = 0.f, a2 = 0.f, a3 = 0.f;
    for (unsigned j = s; j < e; ++j) {
        unsigned src = col[j];
        ushort4 v = *(const ushort4*)(xb + (size_t)src * FEAT + lane * 4);
        a0 += bf2f(v.x); a1 += bf2f(v.y); a2 += bf2f(v.z); a3 += bf2f(v.w);
    }
    float r = 1.0f / fmaxf((float)(e - s), 1.0f);
    ushort4 o = make_ushort4(f2bf(a0 * r), f2bf(a1 * r), f2bf(a2 * r), f2bf(a3 * r));
    *(ushort4*)(meanb + (size_t)node * FEAT + lane * 4) = o;
}

// ============================================================================
// Fused GEMM: xbn = bf16( relu([meanb|x] @ [Wl|Wr]^T + bl) + x )
// BM=128, BN=256, BK=32, 8 waves (2x4 of 64x64).
// One-barrier-per-phase counted pipeline + coalesced LDS epilogue (R9).
// ============================================================================
#define ATILE 4096   // ushorts: 128 rows x 32 elems = 8 KB
#define BTILE 8192   // ushorts: 256 rows x 32 elems = 16 KB
#define CPAD  264    // epilogue row stride (256 + 8)

__global__ __launch_bounds__(512) void gemm_kernel(const ushort* __restrict__ A0,   // meanb
                                                   const ushort* __restrict__ A1,   // x (bf16), also residual
                                                   const ushort* __restrict__ B0,   // Wl slice [256][256]
                                                   const ushort* __restrict__ B1,   // Wr slice
                                                   const float* __restrict__ bias,  // bl slice [256]
                                                   ushort* __restrict__ xbn) {      // next-layer x
    __shared__ ushort lds[36864];                    // 72 KB
    ushort (*As)[ATILE] = (ushort(*)[ATILE])lds;                 // 3 x 8 KB
    ushort (*Bs)[BTILE] = (ushort(*)[BTILE])(lds + 3 * ATILE);   // 3 x 16 KB
    ushort* Cs = lds;                                // epilogue reuse: [128][264] = 66 KB

    const int tid  = threadIdx.x;
    const int lane = tid & 63;
    const int wid  = tid >> 6;          // 0..7
    const int wr   = wid >> 2;          // 0..1  (row half of 128)
    const int wc   = wid & 3;           // 0..3  (col quarter of 256)
    const int row0 = blockIdx.x * 128;

    v4f acc[4][4] = {};

    const int fr  = lane & 15;
    const int cbk = (lane >> 4) << 4;   // frag byte col within 64B row: 0,16,32,48

    // ---- staging address precompute (kt-invariant parts) ----
    const int pA  = tid >> 3;
    const int w0A = ((tid & 7) ^ (pA & 7)) << 4;
    int rA = row0 + 2 * pA + (w0A >> 6);
    rA = rA < N_NODES ? rA : N_NODES - 1;
    const int cbA = w0A & 63;
    const int pB0  = tid >> 3;
    const int w0B0 = ((tid & 7) ^ (pB0 & 7)) << 4;
    const int rB0  = 2 * pB0 + (w0B0 >> 6);
    const int cbB0 = w0B0 & 63;
    const int c1   = tid + 512;
    const int pB1  = c1 >> 3;
    const int w0B1 = ((c1 & 7) ^ (pB1 & 7)) << 4;
    const int rB1  = 2 * pB1 + (w0B1 >> 6);
    const int cbB1 = w0B1 & 63;

    #define STAGE(buf, kt) do {                                                   \
        const ushort* Asrc = ((kt) < 8) ? A0 : A1;                                \
        const ushort* Bsrc = ((kt) < 8) ? B0 : B1;                                \
        const int kb = ((kt) & 7) * 32;                                           \
        gload16(Asrc + (size_t)rA  * FEAT + kb + (cbA  >> 1), &As[buf][tid * 8]); \
        gload16(Bsrc + (size_t)rB0 * FEAT + kb + (cbB0 >> 1), &Bs[buf][tid * 8]); \
        gload16(Bsrc + (size_t)rB1 * FEAT + kb + (cbB1 >> 1), &Bs[buf][(size_t)c1 * 8]); \
    } while (0)

    #define FRAG(basePtr, row) \
        (*(const v8s*)((const char*)(basePtr) + (((row) >> 1) * 128 + \
            ((((row) & 1) << 6) + cbk) ^ ((((row) >> 1) & 7) << 4))))

    #define DSREAD(buf) do {                                                      \
        _Pragma("unroll")                                                         \
        for (int i = 0; i < 4; ++i) a[i] = FRAG(As[buf], wr * 64 + i * 16 + fr);  \
        _Pragma("unroll")                                                         \
        for (int j = 0; j < 4; ++j) b[j] = FRAG(Bs[buf], wc * 64 + j * 16 + fr);  \
    } while (0)

    #define MFMA16() do {                                                         \
        _Pragma("unroll")                                                         \
        for (int i = 0; i < 4; ++i)                                               \
            _Pragma("unroll")                                                     \
            for (int j = 0; j < 4; ++j)                                           \
                acc[i][j] = __builtin_amdgcn_mfma_f32_16x16x32_bf16(a[i], b[j], acc[i][j], 0, 0, 0); \
    } while (0)

    STAGE(0, 0);
    STAGE(1, 1);
    int bufC = 0, bufS = 2;
    v8s a[4], b[4];
    #pragma unroll 1
    for (int kt = 0; kt < 15; ++kt) {
        asm volatile("s_waitcnt vmcnt(3)" ::: "memory");
        __builtin_amdgcn_s_barrier();          // all waves: tile kt landed; buf[bufS] free
        __builtin_amdgcn_sched_barrier(0);
        if (kt <= 13) STAGE(bufS, kt + 2);     // in flight across the next 2 phases
        DSREAD(bufC);
        asm volatile("s_waitcnt lgkmcnt(0)" ::: "memory");
        __builtin_amdgcn_sched_barrier(0);
        __builtin_amdgcn_s_setprio(1);
        MFMA16();
        __builtin_amdgcn_s_setprio(0);
        bufC = (bufC == 2) ? 0 : bufC + 1;
        bufS = (bufS == 2) ? 0 : bufS + 1;
    }
    // final phase: tile 15
    asm volatile("s_waitcnt vmcnt(0)" ::: "memory");
    __builtin_amdgcn_s_barrier();
    __builtin_amdgcn_sched_barrier(0);
    DSREAD(bufC);
    asm volatile("s_waitcnt lgkmcnt(0)" ::: "memory");
    __builtin_amdgcn_sched_barrier(0);
    MFMA16();

    // ================= epilogue =================
    // 1) acc (+bias, relu) -> Cs[128][264] bf16
    __builtin_amdgcn_s_barrier();              // all waves done with As/Bs ring
    {
        const int orow = (lane >> 4) * 4;
        const int ocol = lane & 15;
        #pragma unroll
        for (int j = 0; j < 4; ++j) {
            int colg = wc * 64 + j * 16 + ocol;
            float bv = bias[colg];
            #pragma unroll
            for (int i = 0; i < 4; ++i) {
                int rl = wr * 64 + i * 16 + orow;
                #pragma unroll
                for (int r = 0; r < 4; ++r)
                    Cs[(rl + r) * CPAD + colg] = f2bf(fmaxf(acc[i][j][r] + bv, 0.0f));
            }
        }
    }
    __builtin_amdgcn_s_barrier();
    // 2) coalesced residual add + store: thread -> row p*64 + (tid>>3), 4 chunks
    #pragma unroll
    for (int p = 0; p < 2; ++p) {
        int rl  = p * 64 + (tid >> 3);
        int row = row0 + rl;
        #pragma unroll
        for (int it = 0; it < 4; ++it) {
            int c0 = (tid & 7) * 8 + it * 64;
            v8s y = *(const v8s*)(Cs + rl * CPAD + c0);
            if (row < N_NODES) {
                v8s xv = *(const v8s*)(A1 + (size_t)row * FEAT + c0);
                v8s o;
                #pragma unroll
                for (int k = 0; k < 8; ++k)
                    o[k] = (short)f2bf(bf2f((ushort)y[k]) + bf2f((ushort)xv[k]));
                *(v8s*)(xbn + (size_t)row * FEAT + c0) = o;
            }
        }
    }
    #undef STAGE
    #undef FRAG
    #undef DSREAD
    #undef MFMA16
}

// ============================================================================
// Parallel segment softmax: 1 block (512 thr) per graph.
// 16 node-chunks x 32 threads; each thread: 8 feats (ushort8 loads, 16B/lane),
// 8 independent online-softmax states in base-2 (exp2f = native v_exp_f32).
// Merge 16 partial (m,den,acc) per feature via LDS (associative combine).
// ============================================================================
__global__ __launch_bounds__(512) void smax_kernel(const ushort* __restrict__ xb,
                                                   const unsigned* __restrict__ gs,
                                                   const unsigned* __restrict__ ge,
                                                   const float* __restrict__ t,
                                                   float* __restrict__ out) {
    __shared__ float sm[16 * 256];
    __shared__ float sd[16 * 256];
    __shared__ float sa[16 * 256];
    const int g   = blockIdx.x;
    const unsigned s = gs[g], e = ge[g];
    const float tv2 = t[0] * 1.44269504f;   // log2(e) * t
    const int tid = threadIdx.x;
    const int c   = tid >> 5;               // chunk 0..15
    const int f8  = (tid & 31) * 8;         // feature base

    float m[8], den[8], acc[8];
    #pragma unroll
    for (int k = 0; k < 8; ++k) { m[k] = -INFINITY; den[k] = 0.f; acc[k] = 0.f; }

    if (s < e) {
        for (unsigned n = s + c; n < e; n += 16) {
            v8s v = *(const v8s*)(xb + (size_t)n * FEAT + f8);
            #pragma unroll
            for (int k = 0; k < 8; ++k) {
                float xv = bf2f((ushort)v[k]);
                float s2 = xv * tv2;                 // t*x in log2 domain
                float mn = fmaxf(m[k], s2);
                float sc = exp2f(m[k] - mn);         // 0 on first iter
                float w  = exp2f(s2 - mn);
                den[k] = den[k] * sc + w;
                acc[k] = acc[k] * sc + w * xv;
                m[k] = mn;
            }
        }
    }
    #pragma unroll
    for (int k = 0; k < 8; ++k) {
        sm[c * 256 + f8 + k] = m[k];
        sd[c * 256 + f8 + k] = den[k];
        sa[c * 256 + f8 + k] = acc[k];
    }
    __syncthreads();
    if (tid < 256) {
        if (s < e) {
            const int f = tid;
            float M = -INFINITY;
            #pragma unroll
            for (int cc = 0; cc < 16; ++cc) M = fmaxf(M, sm[cc * 256 + f]);
            float D = 0.f, A = 0.f;
            #pragma unroll
            for (int cc = 0; cc < 16; ++cc) {
                float w = exp2f(sm[cc * 256 + f] - M);   // 0 for empty chunks
                D += sd[cc * 256 + f] * w;
                A += sa[cc * 256 + f] * w;
            }
            out[(size_t)g * FEAT + tid] = A / fmaxf(D, 1e-16f);
        } else {
            out[(size_t)g * FEAT + tid] = 0.f;   // empty segment -> 0 per reference
        }
    }
}

extern "C" void kernel_launch(void* const* d_in, const int* in_sizes, int n_in,
                              void* d_out, int out_size, void* d_ws, size_t ws_size,
                              hipStream_t stream) {
    const float* x     = (const float*)d_in[0];
    const int*   ei    = (const int*)d_in[1];    // [2, E]: row0=src, row1=dst
    const int*   batch = (const int*)d_in[2];
    const float* Wl    = (const float*)d_in[3];  // [L, F, F]
    const float* bl    = (const float*)d_in[4];  // [L, F]
    const float* Wr    = (const float*)d_in[5];  // [L, F, F]
    const float* t     = (const float*)d_in[6];  // [1]
    float* out = (float*)d_out;

    const size_t NF2 = (size_t)N_NODES * FEAT * 2;   // 51,200,000
    const size_t WSZ = (size_t)N_LAYERS * FEAT * FEAT * 2;

    char* ws = (char*)d_ws;
    size_t off = 0;
    ushort* xb0   = (ushort*)(ws + off); off += NF2;
    ushort* xb1   = (ushort*)(ws + off); off += NF2;
    ushort* meanb = (ushort*)(ws + off); off += NF2;
    ushort* wlb   = (ushort*)(ws + off); off += WSZ;
    ushort* wrb   = (ushort*)(ws + off); off += WSZ;
    unsigned* degu   = (unsigned*)(ws + off); off += (size_t)N_NODES * 4;
    unsigned* excl   = (unsigned*)(ws + off); off += (size_t)N_NODES * 4;
    unsigned* bsum   = (unsigned*)(ws + off); off += 128 * 4;
    unsigned* rowptr = (unsigned*)(ws + off); off += (size_t)(N_NODES + 1) * 4;
    unsigned* cursor = (unsigned*)(ws + off); off += (size_t)N_NODES * 4;
    unsigned* col    = (unsigned*)(ws + off); off += (size_t)N_EDGES * 4;
    unsigned* gs     = (unsigned*)(ws + off); off += (size_t)N_GRAPHS * 4;
    unsigned* ge     = (unsigned*)(ws + off); off += (size_t)N_GRAPHS * 4;

    hipMemsetAsync(degu, 0, (size_t)N_NODES * 4, stream);
    hipMemsetAsync(gs, 0xFF, (size_t)N_GRAPHS * 4, stream);
    hipMemsetAsync(ge, 0, (size_t)N_GRAPHS * 4, stream);

    init_kernel<<<(N_NODES * FEAT / 4 + 255) / 256, 256, 0, stream>>>(x, xb0);
    wconv_kernel<<<(N_LAYERS * FEAT * FEAT / 4 + 255) / 256, 256, 0, stream>>>(Wl, Wr, wlb, wrb);

    // CSR build
    const int NB_SCAN = (N_NODES + SCAN_B - 1) / SCAN_B;   // 98
    hist_kernel<<<(N_EDGES + 255) / 256, 256, 0, stream>>>(ei + N_EDGES, degu);
    scan_blocks<<<NB_SCAN, SCAN_B, 0, stream>>>(degu, excl, bsum);
    scan_tops<<<1, 1, 0, stream>>>(bsum, NB_SCAN);
    finalize_rowptr<<<(N_NODES + 256) / 256, 256, 0, stream>>>(excl, bsum, rowptr, cursor);
    scatter_kernel<<<(N_EDGES + 255) / 256, 256, 0, stream>>>(ei, cursor, col);

    bounds_kernel<<<(N_NODES + 255) / 256, 256, 0, stream>>>(batch, gs, ge);

    ushort* cur = xb0;
    ushort* nxt = xb1;
    for (int l = 0; l < N_LAYERS; ++l) {
        agg_csr<<<(N_NODES + 3) / 4, 256, 0, stream>>>(rowptr, col, cur, meanb);
        gemm_kernel<<<dim3((N_NODES + 127) / 128), 512, 0, stream>>>(
            meanb, cur,
            wlb + (size_t)l * FEAT * FEAT, wrb + (size_t)l * FEAT * FEAT,
            bl + (size_t)l * FEAT, nxt);
        ushort* tmp = cur; cur = nxt; nxt = tmp;
    }

    smax_kernel<<<N_GRAPHS, 512, 0, stream>>>(cur, gs, ge, t, out);
}

// Round 11
// 605.540 us; speedup vs baseline: 2.4222x; 1.0999x over previous
//
#include <hip/hip_runtime.h>
#include <hip/hip_bf16.h>

#define N_NODES  100000
#define N_EDGES  300000
#define FEAT     256
#define N_GRAPHS 500
#define N_LAYERS 6
#define SCAN_B   1024

typedef __attribute__((ext_vector_type(8))) short v8s;   // 8 x bf16 bits (4 VGPRs)
typedef __attribute__((ext_vector_type(4))) float v4f;   // MFMA accumulator

__device__ __forceinline__ unsigned short f2bf(float f) {
    unsigned u = __float_as_uint(f);
    unsigned r = u + 0x7fffu + ((u >> 16) & 1u);   // RNE
    return (unsigned short)(r >> 16);
}
__device__ __forceinline__ float bf2f(unsigned short b) {
    return __uint_as_float(((unsigned)b) << 16);
}

__device__ __forceinline__ void gload16(const ushort* g, ushort* l) {
    __builtin_amdgcn_global_load_lds((const __attribute__((address_space(1))) void*)g,
                                     (__attribute__((address_space(3))) void*)l,
                                     16, 0, 0);
}

// ---- init: x (f32) -> xb (bf16) ----
__global__ __launch_bounds__(256) void init_kernel(const float* __restrict__ x,
                                                   ushort* __restrict__ xb) {
    int i = blockIdx.x * 256 + threadIdx.x;           // per 4 elements
    if ((size_t)i * 4 >= (size_t)N_NODES * FEAT) return;
    float4 v = ((const float4*)x)[i];
    ((ushort4*)xb)[i] = make_ushort4(f2bf(v.x), f2bf(v.y), f2bf(v.z), f2bf(v.w));
}

// ---- weights f32 -> bf16, all layers at once ----
__global__ __launch_bounds__(256) void wconv_kernel(const float* __restrict__ Wl,
                                                    const float* __restrict__ Wr,
                                                    ushort* __restrict__ wlb,
                                                    ushort* __restrict__ wrb) {
    int i = blockIdx.x * 256 + threadIdx.x;           // per 4 elements
    if ((size_t)i * 4 >= (size_t)N_LAYERS * FEAT * FEAT) return;
    float4 a = ((const float4*)Wl)[i];
    float4 b = ((const float4*)Wr)[i];
    ((ushort4*)wlb)[i] = make_ushort4(f2bf(a.x), f2bf(a.y), f2bf(a.z), f2bf(a.w));
    ((ushort4*)wrb)[i] = make_ushort4(f2bf(b.x), f2bf(b.y), f2bf(b.z), f2bf(b.w));
}

// ================= CSR construction (counting sort by dst) =================

__global__ __launch_bounds__(256) void hist_kernel(const int* __restrict__ dst,
                                                   unsigned* __restrict__ degu) {
    int e = blockIdx.x * 256 + threadIdx.x;
    if (e < N_EDGES) atomicAdd(&degu[dst[e]], 1u);
}

__global__ __launch_bounds__(SCAN_B) void scan_blocks(const unsigned* __restrict__ degu,
                                                      unsigned* __restrict__ excl,
                                                      unsigned* __restrict__ bsum) {
    __shared__ unsigned tmp[SCAN_B];
    int i = blockIdx.x * SCAN_B + threadIdx.x;
    unsigned v = (i < N_NODES) ? degu[i] : 0u;
    tmp[threadIdx.x] = v;
    __syncthreads();
    for (int off = 1; off < SCAN_B; off <<= 1) {
        unsigned add = (threadIdx.x >= off) ? tmp[threadIdx.x - off] : 0u;
        __syncthreads();
        tmp[threadIdx.x] += add;
        __syncthreads();
    }
    if (i < N_NODES) excl[i] = tmp[threadIdx.x] - v;
    if (threadIdx.x == SCAN_B - 1) bsum[blockIdx.x] = tmp[SCAN_B - 1];
}

__global__ void scan_tops(unsigned* __restrict__ bsum, int nb) {
    unsigned run = 0;
    for (int b = 0; b < nb; ++b) { unsigned t = bsum[b]; bsum[b] = run; run += t; }
}

__global__ __launch_bounds__(256) void finalize_rowptr(const unsigned* __restrict__ excl,
                                                       const unsigned* __restrict__ bsum,
                                                       unsigned* __restrict__ rowptr,
                                                       unsigned* __restrict__ cursor) {
    int i = blockIdx.x * 256 + threadIdx.x;
    if (i < N_NODES) {
        unsigned v = excl[i] + bsum[i / SCAN_B];
        rowptr[i] = v;
        cursor[i] = v;
    }
    if (i == N_NODES) rowptr[N_NODES] = N_EDGES;
}

__global__ __launch_bounds__(256) void scatter_kernel(const int* __restrict__ ei,
                                                      unsigned* __restrict__ cursor,
                                                      unsigned* __restrict__ col) {
    int e = blockIdx.x * 256 + threadIdx.x;
    if (e >= N_EDGES) return;
    int d = ei[N_EDGES + e];
    unsigned p = atomicAdd(&cursor[d], 1u);
    col[p] = (unsigned)ei[e];
}

// ---- per-graph [start,end) bounds from sorted batch: boundary detection ----
__global__ __launch_bounds__(256) void bounds_kernel(const int* __restrict__ batch,
                                                     unsigned* __restrict__ gs,
                                                     unsigned* __restrict__ ge) {
    int i = blockIdx.x * 256 + threadIdx.x;
    if (i >= N_NODES) return;
    int g = batch[i];
    int gp = (i == 0) ? -1 : batch[i - 1];
    if (g != gp) gs[g] = (unsigned)i;
    int gn = (i == N_NODES - 1) ? -1 : batch[i + 1];
    if (g != gn) ge[g] = (unsigned)(i + 1);
}

// ============================================================================
// Fused layer v2: mean-gather(64 nodes)->LDS, then
//   xbn = bf16( relu([mean|x] @ [Wl|Wr]^T + bl) + x )
// BM=64, BN=256, BK=32, 8 waves (1x8 col stripes of 32), grid 1563.
// LDS (72 KB -> 2 blocks/CU):
//   Ms  [64][512B] row-major, chunk-XOR swz (byte ^= (row&7)<<4)  32 KB
//   Bs  ring 2 x [256 rows x 32k, 2rows/128B line, XOR swz]       32 KB
//   Xs  ring 2 x [64 rows  x 32k, same scheme]                     8 KB
// R6 fixes: Ms row-major (was 8KB-aligned panels -> 8-way conflicts);
// x staged via global_load_lds (was 4x redundant per-wave global reads).
// Epilogue: R9's coalesced LDS round-trip (Cs reuses lds).
// ============================================================================
#define CPAD  264    // epilogue row stride (256 + 8)

__global__ __launch_bounds__(512, 4) void gemm_kernel(
        const unsigned* __restrict__ rowptr,
        const unsigned* __restrict__ col,
        const ushort* __restrict__ xb,    // cur x (row-major bf16)
        const ushort* __restrict__ B0,    // Wl slice [256][256]
        const ushort* __restrict__ B1,    // Wr slice
        const float*  __restrict__ bias,  // bl slice [256]
        ushort* __restrict__ xbn) {       // next-layer x
    __shared__ ushort lds[36864];         // 72 KB
    ushort* Ms  = lds;                    // 16384 ushorts
    ushort* Bs0 = lds + 16384;
    ushort* Bs1 = lds + 24576;
    ushort* Xs0 = lds + 32768;
    ushort* Xs1 = lds + 34816;
    ushort* Cs  = lds;                    // epilogue reuse [64][CPAD]

    const int tid  = threadIdx.x;
    const int lane = tid & 63;
    const int wid  = tid >> 6;            // 0..7 (col stripe)
    const int row0 = blockIdx.x * 64;

    // ---- staging address precompute ----
    // B: chunks tid and tid+512 over 128 lines (2 rows/128B line)
    const int pB0  = tid >> 3;
    const int w0B0 = ((tid & 7) ^ (pB0 & 7)) << 4;
    const int rB0  = 2 * pB0 + (w0B0 >> 6);
    const int cbB0 = w0B0 & 63;
    const int c1   = tid + 512;
    const int pB1  = c1 >> 3;
    const int w0B1 = ((c1 & 7) ^ (pB1 & 7)) << 4;
    const int rB1  = 2 * pB1 + (w0B1 >> 6);
    const int cbB1 = w0B1 & 63;
    // X: chunk tid (tid<256) over 32 lines
    const int pX   = tid >> 3;
    const int w0X  = ((tid & 7) ^ (pX & 7)) << 4;
    int rX = row0 + 2 * pX + (w0X >> 6);
    rX = rX < N_NODES ? rX : N_NODES - 1;
    const int cbX  = w0X & 63;

    #define STAGE_B(bufPtr, kt) do {                                              \
        const ushort* Bsrc = ((kt) < 8) ? B0 : B1;                                \
        const int kb = ((kt) & 7) * 32;                                           \
        gload16(Bsrc + (size_t)rB0 * FEAT + kb + (cbB0 >> 1), (bufPtr) + tid * 8);\
        gload16(Bsrc + (size_t)rB1 * FEAT + kb + (cbB1 >> 1), (bufPtr) + (size_t)c1 * 8); \
    } while (0)

    #define STAGE_X(bufPtr, kt) do {                                              \
        if (tid < 256) {                                                          \
            const int kb = ((kt) & 7) * 32;                                       \
            gload16(xb + (size_t)rX * FEAT + kb + (cbX >> 1), (bufPtr) + tid * 8);\
        }                                                                          \
    } while (0)

    STAGE_B(Bs0, 0);   // lands during gather

    // ======================= gather: mean -> Ms =======================
    {
        const int h   = lane >> 5;        // half-wave: node parity
        const int l32 = lane & 31;        // 8 feats per lane
        #pragma unroll 1
        for (int p = 0; p < 4; ++p) {
            const int nl = wid * 8 + p * 2 + h;      // local row 0..63
            const int node = row0 + nl;
            unsigned s = 0, e = 0;
            if (node < N_NODES) { s = rowptr[node]; e = rowptr[node + 1]; }
            float a0=0.f,a1=0.f,a2=0.f,a3=0.f,a4=0.f,a5=0.f,a6=0.f,a7=0.f;
            #pragma unroll 1
            for (unsigned base = s; base < e; base += 32) {
                unsigned idx = base + (unsigned)l32;
                int cv = (idx < e) ? (int)col[idx] : 0;
                int n = (int)(e - base); n = n > 32 ? 32 : n;
                #pragma unroll 1
                for (int j = 0; j < n; ++j) {
                    unsigned src = (unsigned)__shfl(cv, (h << 5) + j);
                    v8s v = *(const v8s*)(xb + (size_t)src * FEAT + l32 * 8);
                    a0 += bf2f((ushort)v[0]); a1 += bf2f((ushort)v[1]);
                    a2 += bf2f((ushort)v[2]); a3 += bf2f((ushort)v[3]);
                    a4 += bf2f((ushort)v[4]); a5 += bf2f((ushort)v[5]);
                    a6 += bf2f((ushort)v[6]); a7 += bf2f((ushort)v[7]);
                }
            }
            float r = 1.0f / fmaxf((float)(e - s), 1.0f);
            v8s o;
            o[0]=(short)f2bf(a0*r); o[1]=(short)f2bf(a1*r);
            o[2]=(short)f2bf(a2*r); o[3]=(short)f2bf(a3*r);
            o[4]=(short)f2bf(a4*r); o[5]=(short)f2bf(a5*r);
            o[6]=(short)f2bf(a6*r); o[7]=(short)f2bf(a7*r);
            // row-major + chunk-XOR swizzle: uniform bank spread on write & read
            *(v8s*)((char*)Ms + nl * 512 + ((l32 * 16) ^ ((nl & 7) << 4))) = o;
        }
    }
    __syncthreads();   // Ms ready; B(0) drained (vmcnt 0 implied)

    // ======================= K-loop =======================
    v4f acc[4][2] = {};
    const int fr  = lane & 15;
    const int cbk = (lane >> 4) << 4;     // frag byte col within 64B k-window

    // B/X frag: rows packed 2 per 128B line, XOR swz (verified R4-R10)
    #define FRAG(basePtr, row) \
        (*(const v8s*)((const char*)(basePtr) + (((row) >> 1) * 128 + \
            ((((row) & 1) << 6) + cbk) ^ ((((row) >> 1) & 7) << 4))))

    // Ms frag: row-major 512B rows, chunk-XOR swz
    #define AFRAG_M(kt, row) \
        (*(const v8s*)((const char*)Ms + (row) * 512 + \
            ((((kt) << 6) + cbk) ^ (((row) & 7) << 4))))

    #define PHASE(kt, APART) do {                                                 \
        v8s a[4], b[2];                                                           \
        _Pragma("unroll")                                                         \
        for (int i = 0; i < 4; ++i) a[i] = APART;                                 \
        {                                                                          \
            const ushort* bp = ((kt) & 1) ? Bs1 : Bs0;                            \
            _Pragma("unroll")                                                     \
            for (int j = 0; j < 2; ++j) b[j] = FRAG(bp, wid * 32 + j * 16 + fr);  \
        }                                                                          \
        _Pragma("unroll")                                                         \
        for (int i = 0; i < 4; ++i)                                               \
            _Pragma("unroll")                                                     \
            for (int j = 0; j < 2; ++j)                                           \
                acc[i][j] = __builtin_amdgcn_mfma_f32_16x16x32_bf16(a[i], b[j], acc[i][j], 0, 0, 0); \
    } while (0)

    // phases 0..7: A from Ms
    #pragma unroll
    for (int kt = 0; kt < 8; ++kt) {
        STAGE_B((kt & 1) ? Bs0 : Bs1, kt + 1);        // into other buffer
        if (kt == 7) STAGE_X(Xs0, 8);
        PHASE(kt, AFRAG_M(kt, i * 16 + fr));
        __syncthreads();                               // stage(kt+1) landed; buffers safe
    }
    // phases 8..15: A from Xs ring
    #pragma unroll
    for (int kt = 8; kt < 16; ++kt) {
        if (kt < 15) {
            STAGE_B((kt & 1) ? Bs0 : Bs1, kt + 1);
            STAGE_X((kt & 1) ? Xs0 : Xs1, kt + 1);
        }
        const ushort* xp = (kt & 1) ? Xs1 : Xs0;
        PHASE(kt, FRAG(xp, i * 16 + fr));
        __syncthreads();
    }
    #undef PHASE
    #undef AFRAG_M

    // ================= epilogue (R9 coalesced) =================
    {
        const int orow = (lane >> 4) * 4;
        const int ocol = lane & 15;
        #pragma unroll
        for (int j = 0; j < 2; ++j) {
            int colg = wid * 32 + j * 16 + ocol;
            float bv = bias[colg];
            #pragma unroll
            for (int i = 0; i < 4; ++i) {
                int rl = i * 16 + orow;
                #pragma unroll
                for (int r = 0; r < 4; ++r)
                    Cs[(rl + r) * CPAD + colg] = f2bf(fmaxf(acc[i][j][r] + bv, 0.0f));
            }
        }
    }
    __builtin_amdgcn_s_barrier();
    {
        int rl  = tid >> 3;                  // 0..63
        int row = row0 + rl;
        #pragma unroll
        for (int it = 0; it < 4; ++it) {
            int c0 = (tid & 7) * 8 + it * 64;
            v8s y = *(const v8s*)(Cs + rl * CPAD + c0);
            if (row < N_NODES) {
                v8s xv = *(const v8s*)(xb + (size_t)row * FEAT + c0);
                v8s o;
                #pragma unroll
                for (int k = 0; k < 8; ++k)
                    o[k] = (short)f2bf(bf2f((ushort)y[k]) + bf2f((ushort)xv[k]));
                *(v8s*)(xbn + (size_t)row * FEAT + c0) = o;
            }
        }
    }
    #undef STAGE_B
    #undef STAGE_X
    #undef FRAG
}

// ============================================================================
// Parallel segment softmax (R10): 1 block (512 thr) per graph.
// ============================================================================
__global__ __launch_bounds__(512) void smax_kernel(const ushort* __restrict__ xb,
                                                   const unsigned* __restrict__ gs,
                                                   const unsigned* __restrict__ ge,
                                                   const float* __restrict__ t,
                                                   float* __restrict__ out) {
    __shared__ float sm[16 * 256];
    __shared__ float sd[16 * 256];
    __shared__ float sa[16 * 256];
    const int g   = blockIdx.x;
    const unsigned s = gs[g], e = ge[g];
    const float tv2 = t[0] * 1.44269504f;   // log2(e) * t
    const int tid = threadIdx.x;
    const int c   = tid >> 5;               // chunk 0..15
    const int f8  = (tid & 31) * 8;         // feature base

    float m[8], den[8], acc[8];
    #pragma unroll
    for (int k = 0; k < 8; ++k) { m[k] = -INFINITY; den[k] = 0.f; acc[k] = 0.f; }

    if (s < e) {
        for (unsigned n = s + c; n < e; n += 16) {
            v8s v = *(const v8s*)(xb + (size_t)n * FEAT + f8);
            #pragma unroll
            for (int k = 0; k < 8; ++k) {
                float xv = bf2f((ushort)v[k]);
                float s2 = xv * tv2;                 // t*x in log2 domain
                float mn = fmaxf(m[k], s2);
                float sc = exp2f(m[k] - mn);         // 0 on first iter
                float w  = exp2f(s2 - mn);
                den[k] = den[k] * sc + w;
                acc[k] = acc[k] * sc + w * xv;
                m[k] = mn;
            }
        }
    }
    #pragma unroll
    for (int k = 0; k < 8; ++k) {
        sm[c * 256 + f8 + k] = m[k];
        sd[c * 256 + f8 + k] = den[k];
        sa[c * 256 + f8 + k] = acc[k];
    }
    __syncthreads();
    if (tid < 256) {
        if (s < e) {
            const int f = tid;
            float M = -INFINITY;
            #pragma unroll
            for (int cc = 0; cc < 16; ++cc) M = fmaxf(M, sm[cc * 256 + f]);
            float D = 0.f, A = 0.f;
            #pragma unroll
            for (int cc = 0; cc < 16; ++cc) {
                float w = exp2f(sm[cc * 256 + f] - M);   // 0 for empty chunks
                D += sd[cc * 256 + f] * w;
                A += sa[cc * 256 + f] * w;
            }
            out[(size_t)g * FEAT + tid] = A / fmaxf(D, 1e-16f);
        } else {
            out[(size_t)g * FEAT + tid] = 0.f;   // empty segment -> 0 per reference
        }
    }
}

extern "C" void kernel_launch(void* const* d_in, const int* in_sizes, int n_in,
                              void* d_out, int out_size, void* d_ws, size_t ws_size,
                              hipStream_t stream) {
    const float* x     = (const float*)d_in[0];
    const int*   ei    = (const int*)d_in[1];    // [2, E]: row0=src, row1=dst
    const int*   batch = (const int*)d_in[2];
    const float* Wl    = (const float*)d_in[3];  // [L, F, F]
    const float* bl    = (const float*)d_in[4];  // [L, F]
    const float* Wr    = (const float*)d_in[5];  // [L, F, F]
    const float* t     = (const float*)d_in[6];  // [1]
    float* out = (float*)d_out;

    const size_t NF2 = (size_t)N_NODES * FEAT * 2;   // 51,200,000
    const size_t WSZ = (size_t)N_LAYERS * FEAT * FEAT * 2;

    char* ws = (char*)d_ws;
    size_t off = 0;
    ushort* xb0   = (ushort*)(ws + off); off += NF2;
    ushort* xb1   = (ushort*)(ws + off); off += NF2;
    ushort* wlb   = (ushort*)(ws + off); off += WSZ;
    ushort* wrb   = (ushort*)(ws + off); off += WSZ;
    unsigned* degu   = (unsigned*)(ws + off); off += (size_t)N_NODES * 4;
    unsigned* excl   = (unsigned*)(ws + off); off += (size_t)N_NODES * 4;
    unsigned* bsum   = (unsigned*)(ws + off); off += 128 * 4;
    unsigned* rowptr = (unsigned*)(ws + off); off += (size_t)(N_NODES + 1) * 4;
    unsigned* cursor = (unsigned*)(ws + off); off += (size_t)N_NODES * 4;
    unsigned* col    = (unsigned*)(ws + off); off += (size_t)N_EDGES * 4;
    unsigned* gs     = (unsigned*)(ws + off); off += (size_t)N_GRAPHS * 4;
    unsigned* ge     = (unsigned*)(ws + off); off += (size_t)N_GRAPHS * 4;

    hipMemsetAsync(degu, 0, (size_t)N_NODES * 4, stream);
    hipMemsetAsync(gs, 0xFF, (size_t)N_GRAPHS * 4, stream);
    hipMemsetAsync(ge, 0, (size_t)N_GRAPHS * 4, stream);

    init_kernel<<<(N_NODES * FEAT / 4 + 255) / 256, 256, 0, stream>>>(x, xb0);
    wconv_kernel<<<(N_LAYERS * FEAT * FEAT / 4 + 255) / 256, 256, 0, stream>>>(Wl, Wr, wlb, wrb);

    // CSR build
    const int NB_SCAN = (N_NODES + SCAN_B - 1) / SCAN_B;   // 98
    hist_kernel<<<(N_EDGES + 255) / 256, 256, 0, stream>>>(ei + N_EDGES, degu);
    scan_blocks<<<NB_SCAN, SCAN_B, 0, stream>>>(degu, excl, bsum);
    scan_tops<<<1, 1, 0, stream>>>(bsum, NB_SCAN);
    finalize_rowptr<<<(N_NODES + 256) / 256, 256, 0, stream>>>(excl, bsum, rowptr, cursor);
    scatter_kernel<<<(N_EDGES + 255) / 256, 256, 0, stream>>>(ei, cursor, col);

    bounds_kernel<<<(N_NODES + 255) / 256, 256, 0, stream>>>(batch, gs, ge);

    ushort* cur = xb0;
    ushort* nxt = xb1;
    for (int l = 0; l < N_LAYERS; ++l) {
        gemm_kernel<<<dim3((N_NODES + 63) / 64), 512, 0, stream>>>(
            rowptr, col, cur,
            wlb + (size_t)l * FEAT * FEAT, wrb + (size_t)l * FEAT * FEAT,
            bl + (size_t)l * FEAT, nxt);
        ushort* tmp = cur; cur = nxt; nxt = tmp;
    }

    smax_kernel<<<N_GRAPHS, 512, 0, stream>>>(cur, gs, ge, t, out);
}

// Round 12
// 575.026 us; speedup vs baseline: 2.5507x; 1.0531x over previous
//
#include <hip/hip_runtime.h>
#include <hip/hip_bf16.h>

#define N_NODES  100000
#define N_EDGES  300000
#define FEAT     256
#define N_GRAPHS 500
#define N_LAYERS 6
#define SCAN_B   1024

typedef __attribute__((ext_vector_type(8))) short v8s;   // 8 x bf16 bits (4 VGPRs)
typedef __attribute__((ext_vector_type(4))) float v4f;   // MFMA accumulator

__device__ __forceinline__ unsigned short f2bf(float f) {
    unsigned u = __float_as_uint(f);
    unsigned r = u + 0x7fffu + ((u >> 16) & 1u);   // RNE
    return (unsigned short)(r >> 16);
}
__device__ __forceinline__ float bf2f(unsigned short b) {
    return __uint_as_float(((unsigned)b) << 16);
}

__device__ __forceinline__ void gload16(const ushort* g, ushort* l) {
    __builtin_amdgcn_global_load_lds((const __attribute__((address_space(1))) void*)g,
                                     (__attribute__((address_space(3))) void*)l,
                                     16, 0, 0);
}

// ---- init: x (f32) -> xb (bf16) ----
__global__ __launch_bounds__(256) void init_kernel(const float* __restrict__ x,
                                                   ushort* __restrict__ xb) {
    int i = blockIdx.x * 256 + threadIdx.x;           // per 4 elements
    if ((size_t)i * 4 >= (size_t)N_NODES * FEAT) return;
    float4 v = ((const float4*)x)[i];
    ((ushort4*)xb)[i] = make_ushort4(f2bf(v.x), f2bf(v.y), f2bf(v.z), f2bf(v.w));
}

// ---- weights f32 -> bf16, all layers at once ----
__global__ __launch_bounds__(256) void wconv_kernel(const float* __restrict__ Wl,
                                                    const float* __restrict__ Wr,
                                                    ushort* __restrict__ wlb,
                                                    ushort* __restrict__ wrb) {
    int i = blockIdx.x * 256 + threadIdx.x;           // per 4 elements
    if ((size_t)i * 4 >= (size_t)N_LAYERS * FEAT * FEAT) return;
    float4 a = ((const float4*)Wl)[i];
    float4 b = ((const float4*)Wr)[i];
    ((ushort4*)wlb)[i] = make_ushort4(f2bf(a.x), f2bf(a.y), f2bf(a.z), f2bf(a.w));
    ((ushort4*)wrb)[i] = make_ushort4(f2bf(b.x), f2bf(b.y), f2bf(b.z), f2bf(b.w));
}

// ================= CSR construction (counting sort by dst) =================

__global__ __launch_bounds__(256) void hist_kernel(const int* __restrict__ dst,
                                                   unsigned* __restrict__ degu) {
    int e = blockIdx.x * 256 + threadIdx.x;
    if (e < N_EDGES) atomicAdd(&degu[dst[e]], 1u);
}

__global__ __launch_bounds__(SCAN_B) void scan_blocks(const unsigned* __restrict__ degu,
                                                      unsigned* __restrict__ excl,
                                                      unsigned* __restrict__ bsum) {
    __shared__ unsigned tmp[SCAN_B];
    int i = blockIdx.x * SCAN_B + threadIdx.x;
    unsigned v = (i < N_NODES) ? degu[i] : 0u;
    tmp[threadIdx.x] = v;
    __syncthreads();
    for (int off = 1; off < SCAN_B; off <<= 1) {
        unsigned add = (threadIdx.x >= off) ? tmp[threadIdx.x - off] : 0u;
        __syncthreads();
        tmp[threadIdx.x] += add;
        __syncthreads();
    }
    if (i < N_NODES) excl[i] = tmp[threadIdx.x] - v;
    if (threadIdx.x == SCAN_B - 1) bsum[blockIdx.x] = tmp[SCAN_B - 1];
}

__global__ void scan_tops(unsigned* __restrict__ bsum, int nb) {
    unsigned run = 0;
    for (int b = 0; b < nb; ++b) { unsigned t = bsum[b]; bsum[b] = run; run += t; }
}

__global__ __launch_bounds__(256) void finalize_rowptr(const unsigned* __restrict__ excl,
                                                       const unsigned* __restrict__ bsum,
                                                       unsigned* __restrict__ rowptr,
                                                       unsigned* __restrict__ cursor) {
    int i = blockIdx.x * 256 + threadIdx.x;
    if (i < N_NODES) {
        unsigned v = excl[i] + bsum[i / SCAN_B];
        rowptr[i] = v;
        cursor[i] = v;
    }
    if (i == N_NODES) rowptr[N_NODES] = N_EDGES;
}

__global__ __launch_bounds__(256) void scatter_kernel(const int* __restrict__ ei,
                                                      unsigned* __restrict__ cursor,
                                                      unsigned* __restrict__ col) {
    int e = blockIdx.x * 256 + threadIdx.x;
    if (e >= N_EDGES) return;
    int d = ei[N_EDGES + e];
    unsigned p = atomicAdd(&cursor[d], 1u);
    col[p] = (unsigned)ei[e];
}

// ---- per-graph [start,end) bounds from sorted batch: boundary detection ----
__global__ __launch_bounds__(256) void bounds_kernel(const int* __restrict__ batch,
                                                     unsigned* __restrict__ gs,
                                                     unsigned* __restrict__ ge) {
    int i = blockIdx.x * 256 + threadIdx.x;
    if (i >= N_NODES) return;
    int g = batch[i];
    int gp = (i == 0) ? -1 : batch[i - 1];
    if (g != gp) gs[g] = (unsigned)i;
    int gn = (i == N_NODES - 1) ? -1 : batch[i + 1];
    if (g != gn) ge[g] = (unsigned)(i + 1);
}

// ============================================================================
// Fused layer v3: mean-gather(64 nodes)->LDS, then
//   xbn = bf16( relu([mean|x] @ [Wl|Wr]^T + bl) + x )
// BM=64, BN=256, BK=32, 8 waves (1x8 col stripes of 32), grid 1563.
// v3 change: gather edge loop batched 4-wide (4 independent shfl+load chains
// in flight) + node-pair loop unrolled x2 -> serial latency ~4x shorter.
// ============================================================================
#define CPAD  264    // epilogue row stride (256 + 8)

__global__ __launch_bounds__(512, 4) void gemm_kernel(
        const unsigned* __restrict__ rowptr,
        const unsigned* __restrict__ col,
        const ushort* __restrict__ xb,    // cur x (row-major bf16)
        const ushort* __restrict__ B0,    // Wl slice [256][256]
        const ushort* __restrict__ B1,    // Wr slice
        const float*  __restrict__ bias,  // bl slice [256]
        ushort* __restrict__ xbn) {       // next-layer x
    __shared__ ushort lds[36864];         // 72 KB
    ushort* Ms  = lds;                    // 16384 ushorts
    ushort* Bs0 = lds + 16384;
    ushort* Bs1 = lds + 24576;
    ushort* Xs0 = lds + 32768;
    ushort* Xs1 = lds + 34816;
    ushort* Cs  = lds;                    // epilogue reuse [64][CPAD]

    const int tid  = threadIdx.x;
    const int lane = tid & 63;
    const int wid  = tid >> 6;            // 0..7 (col stripe)
    const int row0 = blockIdx.x * 64;

    // ---- staging address precompute ----
    const int pB0  = tid >> 3;
    const int w0B0 = ((tid & 7) ^ (pB0 & 7)) << 4;
    const int rB0  = 2 * pB0 + (w0B0 >> 6);
    const int cbB0 = w0B0 & 63;
    const int c1   = tid + 512;
    const int pB1  = c1 >> 3;
    const int w0B1 = ((c1 & 7) ^ (pB1 & 7)) << 4;
    const int rB1  = 2 * pB1 + (w0B1 >> 6);
    const int cbB1 = w0B1 & 63;
    const int pX   = tid >> 3;
    const int w0X  = ((tid & 7) ^ (pX & 7)) << 4;
    int rX = row0 + 2 * pX + (w0X >> 6);
    rX = rX < N_NODES ? rX : N_NODES - 1;
    const int cbX  = w0X & 63;

    #define STAGE_B(bufPtr, kt) do {                                              \
        const ushort* Bsrc = ((kt) < 8) ? B0 : B1;                                \
        const int kb = ((kt) & 7) * 32;                                           \
        gload16(Bsrc + (size_t)rB0 * FEAT + kb + (cbB0 >> 1), (bufPtr) + tid * 8);\
        gload16(Bsrc + (size_t)rB1 * FEAT + kb + (cbB1 >> 1), (bufPtr) + (size_t)c1 * 8); \
    } while (0)

    #define STAGE_X(bufPtr, kt) do {                                              \
        if (tid < 256) {                                                          \
            const int kb = ((kt) & 7) * 32;                                       \
            gload16(xb + (size_t)rX * FEAT + kb + (cbX >> 1), (bufPtr) + tid * 8);\
        }                                                                          \
    } while (0)

    STAGE_B(Bs0, 0);   // lands during gather

    // ======================= gather: mean -> Ms =======================
    {
        const int h   = lane >> 5;        // half-wave: node parity
        const int l32 = lane & 31;        // 8 feats per lane
        #pragma unroll 2
        for (int p = 0; p < 4; ++p) {
            const int nl = wid * 8 + p * 2 + h;      // local row 0..63
            const int node = row0 + nl;
            unsigned s = 0, e = 0;
            if (node < N_NODES) { s = rowptr[node]; e = rowptr[node + 1]; }
            float a0=0.f,a1=0.f,a2=0.f,a3=0.f,a4=0.f,a5=0.f,a6=0.f,a7=0.f;
            #pragma unroll 1
            for (unsigned base = s; base < e; base += 32) {
                unsigned idx = base + (unsigned)l32;
                int cv = (idx < e) ? (int)col[idx] : 0;
                int n = (int)(e - base); n = n > 32 ? 32 : n;
                int j = 0;
                // 4-wide batches: independent shfl+load chains in flight
                for (; j + 4 <= n; j += 4) {
                    unsigned s0 = (unsigned)__shfl(cv, (h << 5) + j);
                    unsigned s1 = (unsigned)__shfl(cv, (h << 5) + j + 1);
                    unsigned s2 = (unsigned)__shfl(cv, (h << 5) + j + 2);
                    unsigned s3 = (unsigned)__shfl(cv, (h << 5) + j + 3);
                    v8s v0 = *(const v8s*)(xb + (size_t)s0 * FEAT + l32 * 8);
                    v8s v1 = *(const v8s*)(xb + (size_t)s1 * FEAT + l32 * 8);
                    v8s v2 = *(const v8s*)(xb + (size_t)s2 * FEAT + l32 * 8);
                    v8s v3 = *(const v8s*)(xb + (size_t)s3 * FEAT + l32 * 8);
                    a0 += bf2f((ushort)v0[0]) + bf2f((ushort)v1[0]) + bf2f((ushort)v2[0]) + bf2f((ushort)v3[0]);
                    a1 += bf2f((ushort)v0[1]) + bf2f((ushort)v1[1]) + bf2f((ushort)v2[1]) + bf2f((ushort)v3[1]);
                    a2 += bf2f((ushort)v0[2]) + bf2f((ushort)v1[2]) + bf2f((ushort)v2[2]) + bf2f((ushort)v3[2]);
                    a3 += bf2f((ushort)v0[3]) + bf2f((ushort)v1[3]) + bf2f((ushort)v2[3]) + bf2f((ushort)v3[3]);
                    a4 += bf2f((ushort)v0[4]) + bf2f((ushort)v1[4]) + bf2f((ushort)v2[4]) + bf2f((ushort)v3[4]);
                    a5 += bf2f((ushort)v0[5]) + bf2f((ushort)v1[5]) + bf2f((ushort)v2[5]) + bf2f((ushort)v3[5]);
                    a6 += bf2f((ushort)v0[6]) + bf2f((ushort)v1[6]) + bf2f((ushort)v2[6]) + bf2f((ushort)v3[6]);
                    a7 += bf2f((ushort)v0[7]) + bf2f((ushort)v1[7]) + bf2f((ushort)v2[7]) + bf2f((ushort)v3[7]);
                }
                for (; j < n; ++j) {
                    unsigned src = (unsigned)__shfl(cv, (h << 5) + j);
                    v8s v = *(const v8s*)(xb + (size_t)src * FEAT + l32 * 8);
                    a0 += bf2f((ushort)v[0]); a1 += bf2f((ushort)v[1]);
                    a2 += bf2f((ushort)v[2]); a3 += bf2f((ushort)v[3]);
                    a4 += bf2f((ushort)v[4]); a5 += bf2f((ushort)v[5]);
                    a6 += bf2f((ushort)v[6]); a7 += bf2f((ushort)v[7]);
                }
            }
            float r = 1.0f / fmaxf((float)(e - s), 1.0f);
            v8s o;
            o[0]=(short)f2bf(a0*r); o[1]=(short)f2bf(a1*r);
            o[2]=(short)f2bf(a2*r); o[3]=(short)f2bf(a3*r);
            o[4]=(short)f2bf(a4*r); o[5]=(short)f2bf(a5*r);
            o[6]=(short)f2bf(a6*r); o[7]=(short)f2bf(a7*r);
            // row-major + chunk-XOR swizzle: uniform bank spread on write & read
            *(v8s*)((char*)Ms + nl * 512 + ((l32 * 16) ^ ((nl & 7) << 4))) = o;
        }
    }
    __syncthreads();   // Ms ready; B(0) drained

    // ======================= K-loop =======================
    v4f acc[4][2] = {};
    const int fr  = lane & 15;
    const int cbk = (lane >> 4) << 4;     // frag byte col within 64B k-window

    #define FRAG(basePtr, row) \
        (*(const v8s*)((const char*)(basePtr) + (((row) >> 1) * 128 + \
            ((((row) & 1) << 6) + cbk) ^ ((((row) >> 1) & 7) << 4))))

    #define AFRAG_M(kt, row) \
        (*(const v8s*)((const char*)Ms + (row) * 512 + \
            ((((kt) << 6) + cbk) ^ (((row) & 7) << 4))))

    #define PHASE(kt, APART) do {                                                 \
        v8s a[4], b[2];                                                           \
        _Pragma("unroll")                                                         \
        for (int i = 0; i < 4; ++i) a[i] = APART;                                 \
        {                                                                          \
            const ushort* bp = ((kt) & 1) ? Bs1 : Bs0;                            \
            _Pragma("unroll")                                                     \
            for (int j = 0; j < 2; ++j) b[j] = FRAG(bp, wid * 32 + j * 16 + fr);  \
        }                                                                          \
        _Pragma("unroll")                                                         \
        for (int i = 0; i < 4; ++i)                                               \
            _Pragma("unroll")                                                     \
            for (int j = 0; j < 2; ++j)                                           \
                acc[i][j] = __builtin_amdgcn_mfma_f32_16x16x32_bf16(a[i], b[j], acc[i][j], 0, 0, 0); \
    } while (0)

    // phases 0..7: A from Ms
    #pragma unroll
    for (int kt = 0; kt < 8; ++kt) {
        STAGE_B((kt & 1) ? Bs0 : Bs1, kt + 1);        // into other buffer
        if (kt == 7) STAGE_X(Xs0, 8);
        PHASE(kt, AFRAG_M(kt, i * 16 + fr));
        __syncthreads();                               // stage(kt+1) landed; buffers safe
    }
    // phases 8..15: A from Xs ring
    #pragma unroll
    for (int kt = 8; kt < 16; ++kt) {
        if (kt < 15) {
            STAGE_B((kt & 1) ? Bs0 : Bs1, kt + 1);
            STAGE_X((kt & 1) ? Xs0 : Xs1, kt + 1);
        }
        const ushort* xp = (kt & 1) ? Xs1 : Xs0;
        PHASE(kt, FRAG(xp, i * 16 + fr));
        __syncthreads();
    }
    #undef PHASE
    #undef AFRAG_M

    // ================= epilogue (R9 coalesced) =================
    {
        const int orow = (lane >> 4) * 4;
        const int ocol = lane & 15;
        #pragma unroll
        for (int j = 0; j < 2; ++j) {
            int colg = wid * 32 + j * 16 + ocol;
            float bv = bias[colg];
            #pragma unroll
            for (int i = 0; i < 4; ++i) {
                int rl = i * 16 + orow;
                #pragma unroll
                for (int r = 0; r < 4; ++r)
                    Cs[(rl + r) * CPAD + colg] = f2bf(fmaxf(acc[i][j][r] + bv, 0.0f));
            }
        }
    }
    __builtin_amdgcn_s_barrier();
    {
        int rl  = tid >> 3;                  // 0..63
        int row = row0 + rl;
        #pragma unroll
        for (int it = 0; it < 4; ++it) {
            int c0 = (tid & 7) * 8 + it * 64;
            v8s y = *(const v8s*)(Cs + rl * CPAD + c0);
            if (row < N_NODES) {
                v8s xv = *(const v8s*)(xb + (size_t)row * FEAT + c0);
                v8s o;
                #pragma unroll
                for (int k = 0; k < 8; ++k)
                    o[k] = (short)f2bf(bf2f((ushort)y[k]) + bf2f((ushort)xv[k]));
                *(v8s*)(xbn + (size_t)row * FEAT + c0) = o;
            }
        }
    }
    #undef STAGE_B
    #undef STAGE_X
    #undef FRAG
}

// ============================================================================
// Parallel segment softmax (R10): 1 block (512 thr) per graph.
// ============================================================================
__global__ __launch_bounds__(512) void smax_kernel(const ushort* __restrict__ xb,
                                                   const unsigned* __restrict__ gs,
                                                   const unsigned* __restrict__ ge,
                                                   const float* __restrict__ t,
                                                   float* __restrict__ out) {
    __shared__ float sm[16 * 256];
    __shared__ float sd[16 * 256];
    __shared__ float sa[16 * 256];
    const int g   = blockIdx.x;
    const unsigned s = gs[g], e = ge[g];
    const float tv2 = t[0] * 1.44269504f;   // log2(e) * t
    const int tid = threadIdx.x;
    const int c   = tid >> 5;               // chunk 0..15
    const int f8  = (tid & 31) * 8;         // feature base

    float m[8], den[8], acc[8];
    #pragma unroll
    for (int k = 0; k < 8; ++k) { m[k] = -INFINITY; den[k] = 0.f; acc[k] = 0.f; }

    if (s < e) {
        for (unsigned n = s + c; n < e; n += 16) {
            v8s v = *(const v8s*)(xb + (size_t)n * FEAT + f8);
            #pragma unroll
            for (int k = 0; k < 8; ++k) {
                float xv = bf2f((ushort)v[k]);
                float s2 = xv * tv2;                 // t*x in log2 domain
                float mn = fmaxf(m[k], s2);
                float sc = exp2f(m[k] - mn);         // 0 on first iter
                float w  = exp2f(s2 - mn);
                den[k] = den[k] * sc + w;
                acc[k] = acc[k] * sc + w * xv;
                m[k] = mn;
            }
        }
    }
    #pragma unroll
    for (int k = 0; k < 8; ++k) {
        sm[c * 256 + f8 + k] = m[k];
        sd[c * 256 + f8 + k] = den[k];
        sa[c * 256 + f8 + k] = acc[k];
    }
    __syncthreads();
    if (tid < 256) {
        if (s < e) {
            const int f = tid;
            float M = -INFINITY;
            #pragma unroll
            for (int cc = 0; cc < 16; ++cc) M = fmaxf(M, sm[cc * 256 + f]);
            float D = 0.f, A = 0.f;
            #pragma unroll
            for (int cc = 0; cc < 16; ++cc) {
                float w = exp2f(sm[cc * 256 + f] - M);   // 0 for empty chunks
                D += sd[cc * 256 + f] * w;
                A += sa[cc * 256 + f] * w;
            }
            out[(size_t)g * FEAT + tid] = A / fmaxf(D, 1e-16f);
        } else {
            out[(size_t)g * FEAT + tid] = 0.f;   // empty segment -> 0 per reference
        }
    }
}

extern "C" void kernel_launch(void* const* d_in, const int* in_sizes, int n_in,
                              void* d_out, int out_size, void* d_ws, size_t ws_size,
                              hipStream_t stream) {
    const float* x     = (const float*)d_in[0];
    const int*   ei    = (const int*)d_in[1];    // [2, E]: row0=src, row1=dst
    const int*   batch = (const int*)d_in[2];
    const float* Wl    = (const float*)d_in[3];  // [L, F, F]
    const float* bl    = (const float*)d_in[4];  // [L, F]
    const float* Wr    = (const float*)d_in[5];  // [L, F, F]
    const float* t     = (const float*)d_in[6];  // [1]
    float* out = (float*)d_out;

    const size_t NF2 = (size_t)N_NODES * FEAT * 2;   // 51,200,000
    const size_t WSZ = (size_t)N_LAYERS * FEAT * FEAT * 2;

    char* ws = (char*)d_ws;
    size_t off = 0;
    ushort* xb0   = (ushort*)(ws + off); off += NF2;
    ushort* xb1   = (ushort*)(ws + off); off += NF2;
    ushort* wlb   = (ushort*)(ws + off); off += WSZ;
    ushort* wrb   = (ushort*)(ws + off); off += WSZ;
    unsigned* degu   = (unsigned*)(ws + off); off += (size_t)N_NODES * 4;
    unsigned* excl   = (unsigned*)(ws + off); off += (size_t)N_NODES * 4;
    unsigned* bsum   = (unsigned*)(ws + off); off += 128 * 4;
    unsigned* rowptr = (unsigned*)(ws + off); off += (size_t)(N_NODES + 1) * 4;
    unsigned* cursor = (unsigned*)(ws + off); off += (size_t)N_NODES * 4;
    unsigned* col    = (unsigned*)(ws + off); off += (size_t)N_EDGES * 4;
    unsigned* gs     = (unsigned*)(ws + off); off += (size_t)N_GRAPHS * 4;
    unsigned* ge     = (unsigned*)(ws + off); off += (size_t)N_GRAPHS * 4;

    hipMemsetAsync(degu, 0, (size_t)N_NODES * 4, stream);
    hipMemsetAsync(gs, 0xFF, (size_t)N_GRAPHS * 4, stream);
    hipMemsetAsync(ge, 0, (size_t)N_GRAPHS * 4, stream);

    init_kernel<<<(N_NODES * FEAT / 4 + 255) / 256, 256, 0, stream>>>(x, xb0);
    wconv_kernel<<<(N_LAYERS * FEAT * FEAT / 4 + 255) / 256, 256, 0, stream>>>(Wl, Wr, wlb, wrb);

    // CSR build
    const int NB_SCAN = (N_NODES + SCAN_B - 1) / SCAN_B;   // 98
    hist_kernel<<<(N_EDGES + 255) / 256, 256, 0, stream>>>(ei + N_EDGES, degu);
    scan_blocks<<<NB_SCAN, SCAN_B, 0, stream>>>(degu, excl, bsum);
    scan_tops<<<1, 1, 0, stream>>>(bsum, NB_SCAN);
    finalize_rowptr<<<(N_NODES + 256) / 256, 256, 0, stream>>>(excl, bsum, rowptr, cursor);
    scatter_kernel<<<(N_EDGES + 255) / 256, 256, 0, stream>>>(ei, cursor, col);

    bounds_kernel<<<(N_NODES + 255) / 256, 256, 0, stream>>>(batch, gs, ge);

    ushort* cur = xb0;
    ushort* nxt = xb1;
    for (int l = 0; l < N_LAYERS; ++l) {
        gemm_kernel<<<dim3((N_NODES + 63) / 64), 512, 0, stream>>>(
            rowptr, col, cur,
            wlb + (size_t)l * FEAT * FEAT, wrb + (size_t)l * FEAT * FEAT,
            bl + (size_t)l * FEAT, nxt);
        ushort* tmp = cur; cur = nxt; nxt = tmp;
    }

    smax_kernel<<<N_GRAPHS, 512, 0, stream>>>(cur, gs, ge, t, out);
}

// Round 13
// 548.359 us; speedup vs baseline: 2.6748x; 1.0486x over previous
//
#include <hip/hip_runtime.h>
#include <hip/hip_bf16.h>

#define N_NODES  100000
#define N_EDGES  300000
#define FEAT     256
#define N_GRAPHS 500
#define N_LAYERS 6
#define SCAN_B   1024

typedef __attribute__((ext_vector_type(8))) short v8s;   // 8 x bf16 bits (4 VGPRs)
typedef __attribute__((ext_vector_type(4))) float v4f;   // MFMA accumulator

__device__ __forceinline__ unsigned short f2bf(float f) {
    unsigned u = __float_as_uint(f);
    unsigned r = u + 0x7fffu + ((u >> 16) & 1u);   // RNE
    return (unsigned short)(r >> 16);
}
__device__ __forceinline__ float bf2f(unsigned short b) {
    return __uint_as_float(((unsigned)b) << 16);
}

__device__ __forceinline__ void gload16(const ushort* g, ushort* l) {
    __builtin_amdgcn_global_load_lds((const __attribute__((address_space(1))) void*)g,
                                     (__attribute__((address_space(3))) void*)l,
                                     16, 0, 0);
}

// ---- init: x (f32) -> xb (bf16) ----
__global__ __launch_bounds__(256) void init_kernel(const float* __restrict__ x,
                                                   ushort* __restrict__ xb) {
    int i = blockIdx.x * 256 + threadIdx.x;           // per 4 elements
    if ((size_t)i * 4 >= (size_t)N_NODES * FEAT) return;
    float4 v = ((const float4*)x)[i];
    ((ushort4*)xb)[i] = make_ushort4(f2bf(v.x), f2bf(v.y), f2bf(v.z), f2bf(v.w));
}

// ---- weights f32 -> bf16, all layers at once ----
__global__ __launch_bounds__(256) void wconv_kernel(const float* __restrict__ Wl,
                                                    const float* __restrict__ Wr,
                                                    ushort* __restrict__ wlb,
                                                    ushort* __restrict__ wrb) {
    int i = blockIdx.x * 256 + threadIdx.x;           // per 4 elements
    if ((size_t)i * 4 >= (size_t)N_LAYERS * FEAT * FEAT) return;
    float4 a = ((const float4*)Wl)[i];
    float4 b = ((const float4*)Wr)[i];
    ((ushort4*)wlb)[i] = make_ushort4(f2bf(a.x), f2bf(a.y), f2bf(a.z), f2bf(a.w));
    ((ushort4*)wrb)[i] = make_ushort4(f2bf(b.x), f2bf(b.y), f2bf(b.z), f2bf(b.w));
}

// ================= CSR construction (counting sort by dst) =================

__global__ __launch_bounds__(256) void hist_kernel(const int* __restrict__ dst,
                                                   unsigned* __restrict__ degu) {
    int e = blockIdx.x * 256 + threadIdx.x;
    if (e < N_EDGES) atomicAdd(&degu[dst[e]], 1u);
}

__global__ __launch_bounds__(SCAN_B) void scan_blocks(const unsigned* __restrict__ degu,
                                                      unsigned* __restrict__ excl,
                                                      unsigned* __restrict__ bsum) {
    __shared__ unsigned tmp[SCAN_B];
    int i = blockIdx.x * SCAN_B + threadIdx.x;
    unsigned v = (i < N_NODES) ? degu[i] : 0u;
    tmp[threadIdx.x] = v;
    __syncthreads();
    for (int off = 1; off < SCAN_B; off <<= 1) {
        unsigned add = (threadIdx.x >= off) ? tmp[threadIdx.x - off] : 0u;
        __syncthreads();
        tmp[threadIdx.x] += add;
        __syncthreads();
    }
    if (i < N_NODES) excl[i] = tmp[threadIdx.x] - v;
    if (threadIdx.x == SCAN_B - 1) bsum[blockIdx.x] = tmp[SCAN_B - 1];
}

__global__ void scan_tops(unsigned* __restrict__ bsum, int nb) {
    unsigned run = 0;
    for (int b = 0; b < nb; ++b) { unsigned t = bsum[b]; bsum[b] = run; run += t; }
}

__global__ __launch_bounds__(256) void finalize_rowptr(const unsigned* __restrict__ excl,
                                                       const unsigned* __restrict__ bsum,
                                                       unsigned* __restrict__ rowptr,
                                                       unsigned* __restrict__ cursor) {
    int i = blockIdx.x * 256 + threadIdx.x;
    if (i < N_NODES) {
        unsigned v = excl[i] + bsum[i / SCAN_B];
        rowptr[i] = v;
        cursor[i] = v;
    }
    if (i == N_NODES) rowptr[N_NODES] = N_EDGES;
}

__global__ __launch_bounds__(256) void scatter_kernel(const int* __restrict__ ei,
                                                      unsigned* __restrict__ cursor,
                                                      unsigned* __restrict__ col) {
    int e = blockIdx.x * 256 + threadIdx.x;
    if (e >= N_EDGES) return;
    int d = ei[N_EDGES + e];
    unsigned p = atomicAdd(&cursor[d], 1u);
    col[p] = (unsigned)ei[e];
}

// ---- per-graph [start,end) bounds from sorted batch: boundary detection ----
__global__ __launch_bounds__(256) void bounds_kernel(const int* __restrict__ batch,
                                                     unsigned* __restrict__ gs,
                                                     unsigned* __restrict__ ge) {
    int i = blockIdx.x * 256 + threadIdx.x;
    if (i >= N_NODES) return;
    int g = batch[i];
    int gp = (i == 0) ? -1 : batch[i - 1];
    if (g != gp) gs[g] = (unsigned)i;
    int gn = (i == N_NODES - 1) ? -1 : batch[i + 1];
    if (g != gn) ge[g] = (unsigned)(i + 1);
}

// ============================================================================
// Fused layer v4: mean-gather(64 nodes)->LDS, then
//   xbn = bf16( relu([mean|x] @ [Wl|Wr]^T + bl) + x )
// BM=64, BN=256, BK=32, 8 waves (1x8 col stripes of 32), grid 1563.
// v4 changes vs v3:
//  (1) gather: masked 4-wide batches (clamped idx + 0/1 weight) -> every node
//      row needs only ceil(deg/4) latency rounds (deg<=4: ONE).
//  (2) K-loop: wait-then-issue phases — vmcnt(0) at phase top drains only the
//      stage issued a FULL PHASE earlier (residual ~0), ONE barrier per phase,
//      stage(kt+1) issued after the barrier, setprio around MFMA cluster.
// ============================================================================
#define CPAD  264    // epilogue row stride (256 + 8)

__global__ __launch_bounds__(512, 4) void gemm_kernel(
        const unsigned* __restrict__ rowptr,
        const unsigned* __restrict__ col,
        const ushort* __restrict__ xb,    // cur x (row-major bf16)
        const ushort* __restrict__ B0,    // Wl slice [256][256]
        const ushort* __restrict__ B1,    // Wr slice
        const float*  __restrict__ bias,  // bl slice [256]
        ushort* __restrict__ xbn) {       // next-layer x
    __shared__ ushort lds[36864];         // 72 KB
    ushort* Ms  = lds;                    // 16384 ushorts (32 KB)
    ushort* Bs0 = lds + 16384;
    ushort* Bs1 = lds + 24576;
    ushort* Xs0 = lds + 32768;
    ushort* Xs1 = lds + 34816;
    ushort* Cs  = lds;                    // epilogue reuse [64][CPAD]

    const int tid  = threadIdx.x;
    const int lane = tid & 63;
    const int wid  = tid >> 6;            // 0..7 (col stripe)
    const int row0 = blockIdx.x * 64;

    // ---- staging address precompute ----
    const int pB0  = tid >> 3;
    const int w0B0 = ((tid & 7) ^ (pB0 & 7)) << 4;
    const int rB0  = 2 * pB0 + (w0B0 >> 6);
    const int cbB0 = w0B0 & 63;
    const int c1   = tid + 512;
    const int pB1  = c1 >> 3;
    const int w0B1 = ((c1 & 7) ^ (pB1 & 7)) << 4;
    const int rB1  = 2 * pB1 + (w0B1 >> 6);
    const int cbB1 = w0B1 & 63;
    const int pX   = tid >> 3;
    const int w0X  = ((tid & 7) ^ (pX & 7)) << 4;
    int rX = row0 + 2 * pX + (w0X >> 6);
    rX = rX < N_NODES ? rX : N_NODES - 1;
    const int cbX  = w0X & 63;

    #define STAGE_B(bufPtr, kt) do {                                              \
        const ushort* Bsrc = ((kt) < 8) ? B0 : B1;                                \
        const int kb = ((kt) & 7) * 32;                                           \
        gload16(Bsrc + (size_t)rB0 * FEAT + kb + (cbB0 >> 1), (bufPtr) + tid * 8);\
        gload16(Bsrc + (size_t)rB1 * FEAT + kb + (cbB1 >> 1), (bufPtr) + (size_t)c1 * 8); \
    } while (0)

    #define STAGE_X(bufPtr, kt) do {                                              \
        if (tid < 256) {                                                          \
            const int kb = ((kt) & 7) * 32;                                       \
            gload16(xb + (size_t)rX * FEAT + kb + (cbX >> 1), (bufPtr) + tid * 8);\
        }                                                                          \
    } while (0)

    STAGE_B(Bs0, 0);   // lands during gather

    // ======================= gather: mean -> Ms =======================
    {
        const int h   = lane >> 5;        // half-wave: node parity
        const int l32 = lane & 31;        // 8 feats per lane
        #pragma unroll 2
        for (int p = 0; p < 4; ++p) {
            const int nl = wid * 8 + p * 2 + h;      // local row 0..63
            const int node = row0 + nl;
            unsigned s = 0, e = 0;
            if (node < N_NODES) { s = rowptr[node]; e = rowptr[node + 1]; }
            float a0=0.f,a1=0.f,a2=0.f,a3=0.f,a4=0.f,a5=0.f,a6=0.f,a7=0.f;
            #pragma unroll 1
            for (unsigned base = s; base < e; base += 32) {
                unsigned idx = base + (unsigned)l32;
                int cv = (idx < e) ? (int)col[idx] : 0;
                int n = (int)(e - base); n = n > 32 ? 32 : n;
                // masked 4-wide: ceil(n/4) latency rounds, lanes past n weight 0
                #pragma unroll 1
                for (int j = 0; j < n; j += 4) {
                    int nj = n - 1;
                    int l0 = (h << 5) + j;
                    int l1 = (h << 5) + (j + 1 < n ? j + 1 : nj);
                    int l2 = (h << 5) + (j + 2 < n ? j + 2 : nj);
                    int l3 = (h << 5) + (j + 3 < n ? j + 3 : nj);
                    float m1 = (j + 1 < n) ? 1.f : 0.f;
                    float m2 = (j + 2 < n) ? 1.f : 0.f;
                    float m3 = (j + 3 < n) ? 1.f : 0.f;
                    unsigned s0 = (unsigned)__shfl(cv, l0);
                    unsigned s1 = (unsigned)__shfl(cv, l1);
                    unsigned s2 = (unsigned)__shfl(cv, l2);
                    unsigned s3 = (unsigned)__shfl(cv, l3);
                    v8s v0 = *(const v8s*)(xb + (size_t)s0 * FEAT + l32 * 8);
                    v8s v1 = *(const v8s*)(xb + (size_t)s1 * FEAT + l32 * 8);
                    v8s v2 = *(const v8s*)(xb + (size_t)s2 * FEAT + l32 * 8);
                    v8s v3 = *(const v8s*)(xb + (size_t)s3 * FEAT + l32 * 8);
                    a0 += bf2f((ushort)v0[0]) + m1*bf2f((ushort)v1[0]) + m2*bf2f((ushort)v2[0]) + m3*bf2f((ushort)v3[0]);
                    a1 += bf2f((ushort)v0[1]) + m1*bf2f((ushort)v1[1]) + m2*bf2f((ushort)v2[1]) + m3*bf2f((ushort)v3[1]);
                    a2 += bf2f((ushort)v0[2]) + m1*bf2f((ushort)v1[2]) + m2*bf2f((ushort)v2[2]) + m3*bf2f((ushort)v3[2]);
                    a3 += bf2f((ushort)v0[3]) + m1*bf2f((ushort)v1[3]) + m2*bf2f((ushort)v2[3]) + m3*bf2f((ushort)v3[3]);
                    a4 += bf2f((ushort)v0[4]) + m1*bf2f((ushort)v1[4]) + m2*bf2f((ushort)v2[4]) + m3*bf2f((ushort)v3[4]);
                    a5 += bf2f((ushort)v0[5]) + m1*bf2f((ushort)v1[5]) + m2*bf2f((ushort)v2[5]) + m3*bf2f((ushort)v3[5]);
                    a6 += bf2f((ushort)v0[6]) + m1*bf2f((ushort)v1[6]) + m2*bf2f((ushort)v2[6]) + m3*bf2f((ushort)v3[6]);
                    a7 += bf2f((ushort)v0[7]) + m1*bf2f((ushort)v1[7]) + m2*bf2f((ushort)v2[7]) + m3*bf2f((ushort)v3[7]);
                }
            }
            float r = 1.0f / fmaxf((float)(e - s), 1.0f);
            v8s o;
            o[0]=(short)f2bf(a0*r); o[1]=(short)f2bf(a1*r);
            o[2]=(short)f2bf(a2*r); o[3]=(short)f2bf(a3*r);
            o[4]=(short)f2bf(a4*r); o[5]=(short)f2bf(a5*r);
            o[6]=(short)f2bf(a6*r); o[7]=(short)f2bf(a7*r);
            *(v8s*)((char*)Ms + nl * 512 + ((l32 * 16) ^ ((nl & 7) << 4))) = o;
        }
    }
    __syncthreads();   // Ms ready; B(0) drained (full vmcnt drain)

    // ======================= K-loop (wait-then-issue) =======================
    v4f acc[4][2] = {};
    const int fr  = lane & 15;
    const int cbk = (lane >> 4) << 4;     // frag byte col within 64B k-window

    #define FRAG(basePtr, row) \
        (*(const v8s*)((const char*)(basePtr) + (((row) >> 1) * 128 + \
            ((((row) & 1) << 6) + cbk) ^ ((((row) >> 1) & 7) << 4))))

    #define AFRAG_M(kt, row) \
        (*(const v8s*)((const char*)Ms + (row) * 512 + \
            ((((kt) << 6) + cbk) ^ (((row) & 7) << 4))))

    #pragma unroll
    for (int kt = 0; kt < 16; ++kt) {
        if (kt > 0) {
            // stage(kt) was issued a full phase ago -> residual wait ~0
            asm volatile("s_waitcnt vmcnt(0)" ::: "memory");
            __builtin_amdgcn_s_barrier();      // all waves: stage(kt) landed, phase kt-1 reads done
        }
        if (kt < 15) {
            STAGE_B((kt & 1) ? Bs0 : Bs1, kt + 1);    // into the buffer last read at kt-1
            if (kt == 7) STAGE_X(Xs0, 8);
            if (kt >= 8) STAGE_X((kt & 1) ? Xs0 : Xs1, kt + 1);
        }
        v8s a[4], b[2];
        if (kt < 8) {
            #pragma unroll
            for (int i = 0; i < 4; ++i) a[i] = AFRAG_M(kt, i * 16 + fr);
        } else {
            const ushort* xp = (kt & 1) ? Xs1 : Xs0;
            #pragma unroll
            for (int i = 0; i < 4; ++i) a[i] = FRAG(xp, i * 16 + fr);
        }
        {
            const ushort* bp = (kt & 1) ? Bs1 : Bs0;
            #pragma unroll
            for (int j = 0; j < 2; ++j) b[j] = FRAG(bp, wid * 32 + j * 16 + fr);
        }
        __builtin_amdgcn_s_setprio(1);
        #pragma unroll
        for (int i = 0; i < 4; ++i)
            #pragma unroll
            for (int j = 0; j < 2; ++j)
                acc[i][j] = __builtin_amdgcn_mfma_f32_16x16x32_bf16(a[i], b[j], acc[i][j], 0, 0, 0);
        __builtin_amdgcn_s_setprio(0);
    }
    #undef AFRAG_M

    // ================= epilogue (R9 coalesced) =================
    __builtin_amdgcn_s_barrier();   // all waves past phase-15 reads (Cs overlaps Ms + 1KB Bs0 only)
    {
        const int orow = (lane >> 4) * 4;
        const int ocol = lane & 15;
        #pragma unroll
        for (int j = 0; j < 2; ++j) {
            int colg = wid * 32 + j * 16 + ocol;
            float bv = bias[colg];
            #pragma unroll
            for (int i = 0; i < 4; ++i) {
                int rl = i * 16 + orow;
                #pragma unroll
                for (int r = 0; r < 4; ++r)
                    Cs[(rl + r) * CPAD + colg] = f2bf(fmaxf(acc[i][j][r] + bv, 0.0f));
            }
        }
    }
    __syncthreads();                // ds_writes drained + visible to all waves
    {
        int rl  = tid >> 3;                  // 0..63
        int row = row0 + rl;
        #pragma unroll
        for (int it = 0; it < 4; ++it) {
            int c0 = (tid & 7) * 8 + it * 64;
            v8s y = *(const v8s*)(Cs + rl * CPAD + c0);
            if (row < N_NODES) {
                v8s xv = *(const v8s*)(xb + (size_t)row * FEAT + c0);
                v8s o;
                #pragma unroll
                for (int k = 0; k < 8; ++k)
                    o[k] = (short)f2bf(bf2f((ushort)y[k]) + bf2f((ushort)xv[k]));
                *(v8s*)(xbn + (size_t)row * FEAT + c0) = o;
            }
        }
    }
    #undef STAGE_B
    #undef STAGE_X
    #undef FRAG
}

// ============================================================================
// Parallel segment softmax (R10): 1 block (512 thr) per graph.
// ============================================================================
__global__ __launch_bounds__(512) void smax_kernel(const ushort* __restrict__ xb,
                                                   const unsigned* __restrict__ gs,
                                                   const unsigned* __restrict__ ge,
                                                   const float* __restrict__ t,
                                                   float* __restrict__ out) {
    __shared__ float sm[16 * 256];
    __shared__ float sd[16 * 256];
    __shared__ float sa[16 * 256];
    const int g   = blockIdx.x;
    const unsigned s = gs[g], e = ge[g];
    const float tv2 = t[0] * 1.44269504f;   // log2(e) * t
    const int tid = threadIdx.x;
    const int c   = tid >> 5;               // chunk 0..15
    const int f8  = (tid & 31) * 8;         // feature base

    float m[8], den[8], acc[8];
    #pragma unroll
    for (int k = 0; k < 8; ++k) { m[k] = -INFINITY; den[k] = 0.f; acc[k] = 0.f; }

    if (s < e) {
        for (unsigned n = s + c; n < e; n += 16) {
            v8s v = *(const v8s*)(xb + (size_t)n * FEAT + f8);
            #pragma unroll
            for (int k = 0; k < 8; ++k) {
                float xv = bf2f((ushort)v[k]);
                float s2 = xv * tv2;                 // t*x in log2 domain
                float mn = fmaxf(m[k], s2);
                float sc = exp2f(m[k] - mn);         // 0 on first iter
                float w  = exp2f(s2 - mn);
                den[k] = den[k] * sc + w;
                acc[k] = acc[k] * sc + w * xv;
                m[k] = mn;
            }
        }
    }
    #pragma unroll
    for (int k = 0; k < 8; ++k) {
        sm[c * 256 + f8 + k] = m[k];
        sd[c * 256 + f8 + k] = den[k];
        sa[c * 256 + f8 + k] = acc[k];
    }
    __syncthreads();
    if (tid < 256) {
        if (s < e) {
            const int f = tid;
            float M = -INFINITY;
            #pragma unroll
            for (int cc = 0; cc < 16; ++cc) M = fmaxf(M, sm[cc * 256 + f]);
            float D = 0.f, A = 0.f;
            #pragma unroll
            for (int cc = 0; cc < 16; ++cc) {
                float w = exp2f(sm[cc * 256 + f] - M);   // 0 for empty chunks
                D += sd[cc * 256 + f] * w;
                A += sa[cc * 256 + f] * w;
            }
            out[(size_t)g * FEAT + tid] = A / fmaxf(D, 1e-16f);
        } else {
            out[(size_t)g * FEAT + tid] = 0.f;   // empty segment -> 0 per reference
        }
    }
}

extern "C" void kernel_launch(void* const* d_in, const int* in_sizes, int n_in,
                              void* d_out, int out_size, void* d_ws, size_t ws_size,
                              hipStream_t stream) {
    const float* x     = (const float*)d_in[0];
    const int*   ei    = (const int*)d_in[1];    // [2, E]: row0=src, row1=dst
    const int*   batch = (const int*)d_in[2];
    const float* Wl    = (const float*)d_in[3];  // [L, F, F]
    const float* bl    = (const float*)d_in[4];  // [L, F]
    const float* Wr    = (const float*)d_in[5];  // [L, F, F]
    const float* t     = (const float*)d_in[6];  // [1]
    float* out = (float*)d_out;

    const size_t NF2 = (size_t)N_NODES * FEAT * 2;   // 51,200,000
    const size_t WSZ = (size_t)N_LAYERS * FEAT * FEAT * 2;

    char* ws = (char*)d_ws;
    size_t off = 0;
    ushort* xb0   = (ushort*)(ws + off); off += NF2;
    ushort* xb1   = (ushort*)(ws + off); off += NF2;
    ushort* wlb   = (ushort*)(ws + off); off += WSZ;
    ushort* wrb   = (ushort*)(ws + off); off += WSZ;
    unsigned* degu   = (unsigned*)(ws + off); off += (size_t)N_NODES * 4;
    unsigned* excl   = (unsigned*)(ws + off); off += (size_t)N_NODES * 4;
    unsigned* bsum   = (unsigned*)(ws + off); off += 128 * 4;
    unsigned* rowptr = (unsigned*)(ws + off); off += (size_t)(N_NODES + 1) * 4;
    unsigned* cursor = (unsigned*)(ws + off); off += (size_t)N_NODES * 4;
    unsigned* col    = (unsigned*)(ws + off); off += (size_t)N_EDGES * 4;
    unsigned* gs     = (unsigned*)(ws + off); off += (size_t)N_GRAPHS * 4;
    unsigned* ge     = (unsigned*)(ws + off); off += (size_t)N_GRAPHS * 4;

    hipMemsetAsync(degu, 0, (size_t)N_NODES * 4, stream);
    hipMemsetAsync(gs, 0xFF, (size_t)N_GRAPHS * 4, stream);
    hipMemsetAsync(ge, 0, (size_t)N_GRAPHS * 4, stream);

    init_kernel<<<(N_NODES * FEAT / 4 + 255) / 256, 256, 0, stream>>>(x, xb0);
    wconv_kernel<<<(N_LAYERS * FEAT * FEAT / 4 + 255) / 256, 256, 0, stream>>>(Wl, Wr, wlb, wrb);

    // CSR build
    const int NB_SCAN = (N_NODES + SCAN_B - 1) / SCAN_B;   // 98
    hist_kernel<<<(N_EDGES + 255) / 256, 256, 0, stream>>>(ei + N_EDGES, degu);
    scan_blocks<<<NB_SCAN, SCAN_B, 0, stream>>>(degu, excl, bsum);
    scan_tops<<<1, 1, 0, stream>>>(bsum, NB_SCAN);
    finalize_rowptr<<<(N_NODES + 256) / 256, 256, 0, stream>>>(excl, bsum, rowptr, cursor);
    scatter_kernel<<<(N_EDGES + 255) / 256, 256, 0, stream>>>(ei, cursor, col);

    bounds_kernel<<<(N_NODES + 255) / 256, 256, 0, stream>>>(batch, gs, ge);

    ushort* cur = xb0;
    ushort* nxt = xb1;
    for (int l = 0; l < N_LAYERS; ++l) {
        gemm_kernel<<<dim3((N_NODES + 63) / 64), 512, 0, stream>>>(
            rowptr, col, cur,
            wlb + (size_t)l * FEAT * FEAT, wrb + (size_t)l * FEAT * FEAT,
            bl + (size_t)l * FEAT, nxt);
        ushort* tmp = cur; cur = nxt; nxt = tmp;
    }

    smax_kernel<<<N_GRAPHS, 512, 0, stream>>>(cur, gs, ge, t, out);
}